// Round 17
// baseline (547.230 us; speedup 1.0000x reference)
//
#include <hip/hip_runtime.h>

typedef __attribute__((ext_vector_type(8))) short short8;
typedef __attribute__((ext_vector_type(4))) short short4v;
typedef __attribute__((ext_vector_type(4))) float f32x4;
typedef unsigned short u16;

#define B_    32
#define N_    1176
#define C_    768
#define H_    12
#define HD_   64
#define NMT_  392
#define AG_   49
#define NEGBIG_ (-1.0e4f)

__device__ __forceinline__ u16 f2bf(float f) {
  unsigned u = __float_as_uint(f);
  unsigned r = (u + 0x7fffu + ((u >> 16) & 1u)) >> 16;
  return (u16)r;
}
__device__ __forceinline__ float bf2f(u16 s) {
  return __uint_as_float(((unsigned)s) << 16);
}

// Bijective XCD-chunk swizzle (m204).
__device__ __forceinline__ int xcd_swz(int g, int nwg) {
  const int q = nwg >> 3, r = nwg & 7;
  const int xcd = g & 7, off = g >> 3;
  return (xcd < r ? xcd * (q + 1) : r * (q + 1) + (xcd - r) * q) + off;
}

// ------------------------------------------------------------------
// fp32 -> bf16 hi (and optional lo) split, vectorized.
// ------------------------------------------------------------------
template <int LO>
__global__ __launch_bounds__(256) void splitf(const float* __restrict__ in,
                                              u16* __restrict__ hi,
                                              u16* __restrict__ lo, int n4) {
  int i = blockIdx.x * 256 + threadIdx.x;
  const int stride = gridDim.x * 256;
  for (; i < n4; i += stride) {
    const float4 v = ((const float4*)in)[i];
    const float f[4] = {v.x, v.y, v.z, v.w};
    short4v h, l;
#pragma unroll
    for (int e = 0; e < 4; ++e) {
      u16 hb = f2bf(f[e]);
      h[e] = (short)hb;
      if (LO) l[e] = (short)f2bf(f[e] - bf2f(hb));
    }
    ((short4v*)hi)[i] = h;
    if (LO) ((short4v*)lo)[i] = l;
  }
}

// ------------------------------------------------------------------
// QKV GEMM, plain bf16, BK=64, col-group swizzle (R14) — unchanged.
// ------------------------------------------------------------------
__global__ __launch_bounds__(256, 3) void gemm_qkv(
    const u16* __restrict__ A, const u16* __restrict__ Bw,
    const float* __restrict__ bias, u16* __restrict__ qb, u16* __restrict__ kb,
    u16* __restrict__ vb, int Mch) {
  __shared__ u16 SH[17408];
  u16* As = SH;
  u16* Bs = SH + 8192;
  const int tid = threadIdx.x;
  const int swz = xcd_swz(blockIdx.x, gridDim.x);
  const int half = gridDim.x >> 1;
  const int cg = swz / half;
  const int rem = swz - cg * half;
  const int brow = rem / 9;
  const int bcol = cg * 9 + (rem - brow * 9);
  const int m0 = brow * 128, c0 = bcol * 128;
  const int lane = tid & 63, w = tid >> 6;
  const int wr = w >> 1, wc = w & 1;
  const int fr = lane & 15, ko = lane >> 4;
  const int lsw = (lane * 8) ^ (ko << 4);

  f32x4 acc[4][4];
#pragma unroll
  for (int m = 0; m < 4; ++m)
#pragma unroll
    for (int n = 0; n < 4; ++n) acc[m][n] = (f32x4)0.f;

  short8 ra[4], rb[4];
  auto LOADG = [&](int kt) {
#pragma unroll
    for (int i = 0; i < 4; ++i) {
      const int ch = tid + i * 256;
      const int row = ch >> 3, slotk = ch & 7;
      const int ar = min(m0 + row, Mch - 1);
      ra[i] = *(const short8*)&A[(size_t)ar * 768 + kt * 64 + slotk * 8];
      rb[i] = *(const short8*)&Bw[(size_t)(c0 + row) * 768 + kt * 64 + slotk * 8];
    }
  };
  auto WRITE = [&]() {
#pragma unroll
    for (int i = 0; i < 4; ++i) {
      const int ch = tid + i * 256;
      const int row = ch >> 3, slotk = ch & 7;
      const int s = slotk >> 2, sl = slotk & 3;
      const int off = (row >> 4) * 1024 + s * 512 +
                      ((sl * 128 + (row & 15) * 8) ^ (sl << 4));
      *(short8*)&As[off] = ra[i];
      *(short8*)&Bs[off] = rb[i];
    }
  };

  LOADG(0);
  for (int kt = 0; kt < 12; ++kt) {
    __syncthreads();
    WRITE();
    if (kt < 11) LOADG(kt + 1);
    __syncthreads();
#pragma unroll
    for (int s = 0; s < 2; ++s) {
      short8 af[4], bfr[4];
#pragma unroll
      for (int m = 0; m < 4; ++m)
        af[m] = *(const short8*)&As[((wr * 4 + m) * 2 + s) * 512 + lsw];
#pragma unroll
      for (int n = 0; n < 4; ++n)
        bfr[n] = *(const short8*)&Bs[((wc * 4 + n) * 2 + s) * 512 + lsw];
#pragma unroll
      for (int m = 0; m < 4; ++m)
#pragma unroll
        for (int n = 0; n < 4; ++n)
          acc[m][n] = __builtin_amdgcn_mfma_f32_16x16x32_bf16(af[m], bfr[n], acc[m][n], 0, 0, 0);
    }
  }

  __syncthreads();
  const int t = c0 / 768;
  const int hbase = (c0 % 768) >> 6;
  if (t < 2) {
#pragma unroll
    for (int n = 0; n < 4; ++n) {
      const int col = wc * 64 + n * 16 + fr;
      const float bv = bias[c0 + col];
#pragma unroll
      for (int m = 0; m < 4; ++m)
#pragma unroll
        for (int r = 0; r < 4; ++r) {
          const int row = wr * 64 + m * 16 + ko * 4 + r;
          SH[row * 136 + col] = f2bf(acc[m][n][r] + bv);
        }
    }
    __syncthreads();
    u16* dst = (t == 0) ? qb : kb;
    for (int it = tid; it < 2048; it += 256) {
      const int rt = it >> 4, half2 = (it >> 3) & 1, p = it & 7;
      const int mg = m0 + rt;
      if (mg < Mch) {
        const int bl = mg / N_, nt = mg - bl * N_;
        const short8 vv = *(const short8*)&SH[rt * 136 + half2 * 64 + p * 8];
        *(short8*)&dst[(((size_t)bl * H_ + hbase + half2) * N_ + nt) * 64 + p * 8] = vv;
      }
    }
  } else {
#pragma unroll
    for (int n = 0; n < 4; ++n) {
      const int col = wc * 64 + n * 16 + fr;
      const float bv = bias[c0 + col];
#pragma unroll
      for (int m = 0; m < 4; ++m)
#pragma unroll
        for (int r = 0; r < 4; ++r) {
          const int row = wr * 64 + m * 16 + ko * 4 + r;
          SH[col * 136 + row] = f2bf(acc[m][n][r] + bv);
        }
    }
    __syncthreads();
    for (int it = tid; it < 2048; it += 256) {
      const int ct = it >> 4, tc = it & 15;
      const int mg0 = m0 + tc * 8;
      if (mg0 < Mch) {
        const int bl = mg0 / N_, nt = mg0 - bl * N_;
        const int d = ct & 63, hh = hbase + (ct >> 6);
        const short8 vv = *(const short8*)&SH[ct * 136 + tc * 8];
        *(short8*)&vb[(((size_t)bl * H_ + hh) * 64 + d) * N_ + nt] = vv;
      }
    }
  }
}

// ------------------------------------------------------------------
// Proj GEMM, 2-term: out = Ah@(Bh+Bl)^T + bias (R14) — unchanged.
// ------------------------------------------------------------------
__global__ __launch_bounds__(256, 3) void gemm_proj(
    const u16* __restrict__ Ahg, const u16* __restrict__ Bhg,
    const u16* __restrict__ Blg, const float* __restrict__ bias,
    float* __restrict__ out) {
  __shared__ u16 Ah[8192], Bh[8192], Bl[8192];
  const int tid = threadIdx.x;
  const int swz = xcd_swz(blockIdx.x, gridDim.x);
  const int brow = swz / 6, bcol = swz - brow * 6;
  const int m0 = brow * 128, c0 = bcol * 128;
  const int lane = tid & 63, w = tid >> 6;
  const int wr = w >> 1, wc = w & 1;
  const int fr = lane & 15, ko = lane >> 4;
  const int lsw = (lane * 8) ^ (ko << 4);

  f32x4 acc[4][4];
#pragma unroll
  for (int m = 0; m < 4; ++m)
#pragma unroll
    for (int n = 0; n < 4; ++n) acc[m][n] = (f32x4)0.f;

  short8 rah[4], rbh[4], rbl[4];
  auto LOADG = [&](int kt) {
#pragma unroll
    for (int i = 0; i < 4; ++i) {
      const int ch = tid + i * 256;
      const int row = ch >> 3, slotk = ch & 7;
      const size_t aoff = (size_t)(m0 + row) * 768 + kt * 64 + slotk * 8;
      const size_t boff = (size_t)(c0 + row) * 768 + kt * 64 + slotk * 8;
      rah[i] = *(const short8*)&Ahg[aoff];
      rbh[i] = *(const short8*)&Bhg[boff];
      rbl[i] = *(const short8*)&Blg[boff];
    }
  };
  auto WRITE = [&]() {
#pragma unroll
    for (int i = 0; i < 4; ++i) {
      const int ch = tid + i * 256;
      const int row = ch >> 3, slotk = ch & 7;
      const int s = slotk >> 2, sl = slotk & 3;
      const int off = (row >> 4) * 1024 + s * 512 +
                      ((sl * 128 + (row & 15) * 8) ^ (sl << 4));
      *(short8*)&Ah[off] = rah[i];
      *(short8*)&Bh[off] = rbh[i];
      *(short8*)&Bl[off] = rbl[i];
    }
  };

  LOADG(0);
  for (int kt = 0; kt < 12; ++kt) {
    __syncthreads();
    WRITE();
    if (kt < 11) LOADG(kt + 1);
    __syncthreads();
#pragma unroll
    for (int s = 0; s < 2; ++s) {
      short8 ah[4], bh[4], bl[4];
#pragma unroll
      for (int m = 0; m < 4; ++m)
        ah[m] = *(const short8*)&Ah[((wr * 4 + m) * 2 + s) * 512 + lsw];
#pragma unroll
      for (int n = 0; n < 4; ++n) {
        const int off = ((wc * 4 + n) * 2 + s) * 512 + lsw;
        bh[n] = *(const short8*)&Bh[off];
        bl[n] = *(const short8*)&Bl[off];
      }
#pragma unroll
      for (int m = 0; m < 4; ++m)
#pragma unroll
        for (int n = 0; n < 4; ++n) {
          acc[m][n] = __builtin_amdgcn_mfma_f32_16x16x32_bf16(ah[m], bh[n], acc[m][n], 0, 0, 0);
          acc[m][n] = __builtin_amdgcn_mfma_f32_16x16x32_bf16(ah[m], bl[n], acc[m][n], 0, 0, 0);
        }
    }
  }
#pragma unroll
  for (int n = 0; n < 4; ++n) {
    const int col = c0 + wc * 64 + n * 16 + fr;
    const float bv = bias[col];
#pragma unroll
    for (int m = 0; m < 4; ++m) {
      const int mg = m0 + wr * 64 + m * 16 + ko * 4;
#pragma unroll
      for (int r = 0; r < 4; ++r) out[(size_t)(mg + r) * 768 + col] = acc[m][n][r] + bv;
    }
  }
}

// ------------------------------------------------------------------
// Agent pooling (scrambled reshape); rows 49..63 zeroed.
// ------------------------------------------------------------------
__global__ __launch_bounds__(256) void agent_pool(const u16* __restrict__ q,
                                                  u16* __restrict__ agent) {
  const int wid = threadIdx.x >> 6;
  const int lane = threadIdx.x & 63;
  const int row = blockIdx.x * 4 + wid;
  const int rem = row % (H_ * 64);
  const int b = row / (H_ * 64);
  const int h2 = rem / 64;
  const int a = rem % 64;
  if (a >= AG_) {
    agent[((size_t)b * H_ + h2) * 4096 + a * 64 + lane] = 0;
    return;
  }
  const int ap = a / 7, aq = a % 7;
  float s = 0.f;
#pragma unroll
  for (int i = 0; i < 4; ++i)
#pragma unroll
    for (int j = 0; j < 4; ++j) {
      const int g = (ap * 4 + i) * 336 + (aq * 4 + j) * 12 + h2;
      const int h = g / 784, n = g % 784;
      s += bf2f(q[(((size_t)b * H_ + h) * N_ + NMT_ + n) * HD_ + lane]);
    }
  agent[((size_t)b * H_ + h2) * 4096 + a * 64 + lane] = f2bf(s * 0.0625f);
}

// ------------------------------------------------------------------
// Flash attention R16b: FUSED in-register softmax.
//  - S stays in MFMA-output regs; row max/sum via 4x shfl_xor over the
//    16-lane fr-group (rows w*16+ko*4+r live entirely in that group).
//  - running m/l and the alpha-rescale target (oacc) are in the SAME
//    thread -> Ss/mS/lS/aS LDS arrays deleted; one barrier/kt removed.
//  - Q fragments loaded once directly from global (Qs deleted).
//  - LDS = Ks+Vts+Ps = 24KB -> up to 6 blocks/CU.
//  - Ps swizzle: elem ^= ((row>>2)&3)<<4  (write pxor = ko<<4, read
//    pxor = (fr>>2&3)<<4) -> 32-bank scalar writes, 8-quad b128 reads.
// ------------------------------------------------------------------
__global__ __launch_bounds__(256, 5) void flash_attn(
    const u16* __restrict__ Q, int q_bh_str, int q_base, int q_row_max, int q_valid,
    const u16* __restrict__ K, int k_bh_str, int k_row_max,
    const u16* __restrict__ Vt, int vt_bh_str, int vt_pitch, int vt_col_max,
    int n_keys, int nkt,
    u16* __restrict__ cch, int b0,
    u16* __restrict__ avT, int mode) {
  __shared__ u16 Ks[4096], Vts[4096], Ps[4096];

  const int tid = threadIdx.x, bh = blockIdx.x;
  const int q0 = q_base + blockIdx.y * 56;
  const int lane = tid & 63, w = tid >> 6;
  const int fr = lane & 15, ko = lane >> 4;

  const u16* Qb = Q + (size_t)bh * q_bh_str;
  const u16* Kb = K + (size_t)bh * k_bh_str;
  const u16* Vb = Vt + (size_t)bh * vt_bh_str;

  // Q fragments direct from global, once.
  short8 aq[2];
  {
    const int qr = min(q0 + w * 16 + fr, q_row_max);
#pragma unroll
    for (int s = 0; s < 2; ++s)
      aq[s] = *(const short8*)&Qb[(size_t)qr * 64 + s * 32 + ko * 8];
  }

  float m_[4], l_[4];
#pragma unroll
  for (int r = 0; r < 4; ++r) { m_[r] = NEGBIG_; l_[r] = 0.f; }
  f32x4 oacc[4];
#pragma unroll
  for (int d = 0; d < 4; ++d) oacc[d] = (f32x4)0.f;

  const int wpx = ko << 4;               // Ps write xor (elem idx)
  const int rpx = ((fr >> 2) & 3) << 4;  // Ps read xor

  for (int kt = 0; kt < nkt; ++kt) {
#pragma unroll
    for (int i = 0; i < 2; ++i) {
      const int ch = tid + i * 256;
      const int row = ch >> 3, c8 = (ch & 7) << 3;
      const int kr = min(kt * 64 + row, k_row_max);
      const short8 v = *(const short8*)&Kb[(size_t)kr * 64 + c8];
      *(short8*)&Ks[(row * 64 + c8) ^ ((row & 7) << 3)] = v;
    }
#pragma unroll
    for (int i = 0; i < 2; ++i) {
      const int ch = tid + i * 256;
      const int row = ch >> 3, c8 = (ch & 7) << 3;
      const int col8 = kt * 64 + c8;
      const u16* src = &Vb[(size_t)row * vt_pitch];
      short8 v;
      if (col8 + 8 <= vt_col_max) {
        v = *(const short8*)&src[col8];
      } else {
#pragma unroll
        for (int e = 0; e < 8; ++e) v[e] = (short)src[min(col8 + e, vt_col_max - 1)];
      }
      *(short8*)&Vts[(row * 64 + c8) ^ ((row & 7) << 3)] = v;
    }
    __syncthreads();

    // ---- S = Q K^T (MFMA) -> regs
    f32x4 sa[4];
#pragma unroll
    for (int j = 0; j < 4; ++j) {
      sa[j] = (f32x4)0.f;
#pragma unroll
      for (int s = 0; s < 2; ++s) {
        const short8 bk = *(const short8*)&Ks[((j * 16 + fr) * 64 + s * 32 + ko * 8) ^ ((fr & 7) << 3)];
        sa[j] = __builtin_amdgcn_mfma_f32_16x16x32_bf16(aq[s], bk, sa[j], 0, 0, 0);
      }
    }
    bool mk[4];
#pragma unroll
    for (int j = 0; j < 4; ++j) mk[j] = (kt * 64 + j * 16 + fr) >= n_keys;

    // ---- fused in-register online softmax (per r), Ps write
#pragma unroll
    for (int r = 0; r < 4; ++r) {
      float v[4];
      float mx = NEGBIG_;
#pragma unroll
      for (int j = 0; j < 4; ++j) {
        v[j] = mk[j] ? NEGBIG_ : sa[j][r] * 0.125f;
        mx = fmaxf(mx, v[j]);
      }
      mx = fmaxf(mx, __shfl_xor(mx, 1));
      mx = fmaxf(mx, __shfl_xor(mx, 2));
      mx = fmaxf(mx, __shfl_xor(mx, 4));
      mx = fmaxf(mx, __shfl_xor(mx, 8));
      const float mnew = fmaxf(m_[r], mx);
      const float alpha = __expf(m_[r] - mnew);
      float sum = 0.f;
      u16 pb[4];
#pragma unroll
      for (int j = 0; j < 4; ++j) {
        const float p = mk[j] ? 0.f : __expf(v[j] - mnew);
        sum += p;
        pb[j] = f2bf(p);
      }
      sum += __shfl_xor(sum, 1);
      sum += __shfl_xor(sum, 2);
      sum += __shfl_xor(sum, 4);
      sum += __shfl_xor(sum, 8);
      l_[r] = l_[r] * alpha + sum;
      m_[r] = mnew;
#pragma unroll
      for (int dj = 0; dj < 4; ++dj) oacc[dj][r] *= alpha;
      const int rowb = (w * 16 + ko * 4 + r) * 64;
#pragma unroll
      for (int j = 0; j < 4; ++j) Ps[(rowb + j * 16 + fr) ^ wpx] = pb[j];
    }
    __syncthreads();

    // ---- O += P V (MFMA)
    short8 ap[2];
#pragma unroll
    for (int s = 0; s < 2; ++s)
      ap[s] = *(const short8*)&Ps[((w * 16 + fr) * 64 + s * 32 + ko * 8) ^ rpx];
#pragma unroll
    for (int dj = 0; dj < 4; ++dj) {
      f32x4 o = oacc[dj];
#pragma unroll
      for (int s = 0; s < 2; ++s) {
        const short8 bv = *(const short8*)&Vts[((dj * 16 + fr) * 64 + s * 32 + ko * 8) ^ ((fr & 7) << 3)];
        o = __builtin_amdgcn_mfma_f32_16x16x32_bf16(ap[s], bv, o, 0, 0, 0);
      }
      oacc[dj] = o;
    }
    __syncthreads();
  }

  float linv[4];
#pragma unroll
  for (int r = 0; r < 4; ++r) linv[r] = 1.f / fmaxf(l_[r], 1e-30f);

  if (mode == 0) {
    const int b = bh / H_, h = bh % H_;
#pragma unroll
    for (int dj = 0; dj < 4; ++dj)
#pragma unroll
      for (int r = 0; r < 4; ++r) {
        const int rowl = w * 16 + ko * 4 + r;
        if (rowl < q_valid) {
          const size_t m = (size_t)(b0 + b) * N_ + q0 + rowl;
          cch[m * 768 + h * 64 + dj * 16 + fr] = f2bf(oacc[dj][r] * linv[r]);
        }
      }
  } else {
    // write ALL 64 rows so avT has no unwritten bytes
#pragma unroll
    for (int dj = 0; dj < 4; ++dj)
#pragma unroll
      for (int r = 0; r < 4; ++r) {
        const int a = w * 16 + ko * 4 + r;
        avT[(size_t)bh * 4096 + (dj * 16 + fr) * 64 + a] = f2bf(oacc[dj][r] * linv[r]);
      }
  }
}

// ------------------------------------------------------------------
extern "C" void kernel_launch(void* const* d_in, const int* in_sizes, int n_in,
                              void* d_out, int out_size, void* d_ws,
                              size_t ws_size, hipStream_t stream) {
  const float* x = (const float*)d_in[0];
  const float* qkv_w = (const float*)d_in[1];
  const float* qkv_b = (const float*)d_in[2];
  const float* proj_w = (const float*)d_in[3];
  const float* proj_b = (const float*)d_in[4];
  float* out = (float*)d_out;
  u16* ws = (u16*)d_ws;

  const size_t XBF = 28901376ull;
  const size_t QW = 2304ull * 768;
  const size_t PW = 768ull * 768;
  const size_t QKV1 = (size_t)H_ * N_ * HD_;
  const size_t AG1 = (size_t)H_ * 64 * 64;

  size_t o = 0;
  u16* xbf = ws + o; o += XBF;
  u16* qwh = ws + o; o += QW;
  u16* pwh = ws + o; o += PW;
  u16* pwl = ws + o; o += PW;
  u16* cch = ws + o; o += XBF;
  const size_t fixed_sh = o;
  const size_t per_sh = 3 * QKV1 + 2 * AG1;

  int cb = 1;
  const int cands[6] = {32, 16, 8, 4, 2, 1};
  for (int i = 0; i < 6; ++i)
    if ((fixed_sh + (size_t)cands[i] * per_sh) * 2 <= ws_size) { cb = cands[i]; break; }

  u16* qb = ws + o; o += cb * QKV1;
  u16* kb = ws + o; o += cb * QKV1;
  u16* vb = ws + o; o += cb * QKV1;
  u16* agent = ws + o; o += cb * AG1;
  u16* avT = ws + o; o += cb * AG1;

  splitf<0><<<2048, 256, 0, stream>>>(x, xbf, nullptr, (int)(XBF / 4));
  splitf<0><<<1024, 256, 0, stream>>>(qkv_w, qwh, nullptr, (int)(QW / 4));
  splitf<1><<<512, 256, 0, stream>>>(proj_w, pwh, pwl, (int)(PW / 4));

  const int nch = B_ / cb;
  for (int chn = 0; chn < nch; ++chn) {
    const int b0 = chn * cb;
    const int Mch = cb * N_;
    const int nrow = (Mch + 127) / 128;
    gemm_qkv<<<dim3(nrow * 18), 256, 0, stream>>>(
        xbf + (size_t)b0 * N_ * 768, qwh, qkv_b, qb, kb, vb, Mch);
    agent_pool<<<dim3(cb * 192), 256, 0, stream>>>(qb, agent);
    // agent attention: 49 agents vs all 1176 keys -> avT (d-major)
    flash_attn<<<dim3(cb * H_, 1), 256, 0, stream>>>(
        agent, 4096, 0, 48, AG_, kb, N_ * HD_, N_ - 1,
        vb, N_ * HD_, N_, N_, N_, 19, nullptr, b0, avT, 1);
    // MT attention: 392 x 392
    flash_attn<<<dim3(cb * H_, 7), 256, 0, stream>>>(
        qb, N_ * HD_, 0, N_ - 1, 56, kb, N_ * HD_, N_ - 1,
        vb, N_ * HD_, N_, N_, NMT_, 7, cch, b0, nullptr, 0);
    // q_s attention: 784 x 49 agents
    flash_attn<<<dim3(cb * H_, 14), 256, 0, stream>>>(
        qb, N_ * HD_, NMT_, N_ - 1, 56, agent, 4096, 63,
        avT, 4096, 64, 64, AG_, 1, cch, b0, nullptr, 0);
  }
  gemm_proj<<<dim3(294 * 6), 256, 0, stream>>>(cch, pwh, pwl, proj_b, out);
}

// Round 18
// 519.393 us; speedup vs baseline: 1.0536x; 1.0536x over previous
//
#include <hip/hip_runtime.h>

typedef __attribute__((ext_vector_type(8))) short short8;
typedef __attribute__((ext_vector_type(4))) short short4v;
typedef __attribute__((ext_vector_type(4))) float f32x4;
typedef unsigned short u16;

#define B_    32
#define N_    1176
#define C_    768
#define H_    12
#define HD_   64
#define NMT_  392
#define AG_   49
#define NEGBIG_ (-1.0e4f)

__device__ __forceinline__ u16 f2bf(float f) {
  unsigned u = __float_as_uint(f);
  unsigned r = (u + 0x7fffu + ((u >> 16) & 1u)) >> 16;
  return (u16)r;
}
__device__ __forceinline__ float bf2f(u16 s) {
  return __uint_as_float(((unsigned)s) << 16);
}

// Bijective XCD-chunk swizzle (m204).
__device__ __forceinline__ int xcd_swz(int g, int nwg) {
  const int q = nwg >> 3, r = nwg & 7;
  const int xcd = g & 7, off = g >> 3;
  return (xcd < r ? xcd * (q + 1) : r * (q + 1) + (xcd - r) * q) + off;
}

// ------------------------------------------------------------------
// Combined fp32->bf16 split for x (hi), qkv_w (hi), proj_w (hi+lo).
// One launch, three grid segments (saves 2 launch gaps vs R16).
// ------------------------------------------------------------------
__global__ __launch_bounds__(256) void split_all(
    const float* __restrict__ x, u16* __restrict__ xbf, int n4x,
    const float* __restrict__ qw, u16* __restrict__ qwh, int n4q,
    const float* __restrict__ pw, u16* __restrict__ pwh,
    u16* __restrict__ pwl, int n4p) {
  const int bid = blockIdx.x;
  const float* in;
  u16 *hi, *lo = nullptr;
  int n4, i0, nblk;
  if (bid < 2048) {
    in = x; hi = xbf; n4 = n4x; i0 = bid; nblk = 2048;
  } else if (bid < 3072) {
    in = qw; hi = qwh; n4 = n4q; i0 = bid - 2048; nblk = 1024;
  } else {
    in = pw; hi = pwh; lo = pwl; n4 = n4p; i0 = bid - 3072; nblk = 512;
  }
  int i = i0 * 256 + threadIdx.x;
  const int stride = nblk * 256;
  const bool dolo = (lo != nullptr);
  for (; i < n4; i += stride) {
    const float4 v = ((const float4*)in)[i];
    const float f[4] = {v.x, v.y, v.z, v.w};
    short4v h, l;
#pragma unroll
    for (int e = 0; e < 4; ++e) {
      u16 hb = f2bf(f[e]);
      h[e] = (short)hb;
      l[e] = (short)f2bf(f[e] - bf2f(hb));
    }
    ((short4v*)hi)[i] = h;
    if (dolo) ((short4v*)lo)[i] = l;
  }
}

// ------------------------------------------------------------------
// QKV GEMM, plain bf16, BK=64, col-group swizzle (R14) — unchanged.
// ------------------------------------------------------------------
__global__ __launch_bounds__(256, 3) void gemm_qkv(
    const u16* __restrict__ A, const u16* __restrict__ Bw,
    const float* __restrict__ bias, u16* __restrict__ qb, u16* __restrict__ kb,
    u16* __restrict__ vb, int Mch) {
  __shared__ u16 SH[17408];
  u16* As = SH;
  u16* Bs = SH + 8192;
  const int tid = threadIdx.x;
  const int swz = xcd_swz(blockIdx.x, gridDim.x);
  const int half = gridDim.x >> 1;
  const int cg = swz / half;
  const int rem = swz - cg * half;
  const int brow = rem / 9;
  const int bcol = cg * 9 + (rem - brow * 9);
  const int m0 = brow * 128, c0 = bcol * 128;
  const int lane = tid & 63, w = tid >> 6;
  const int wr = w >> 1, wc = w & 1;
  const int fr = lane & 15, ko = lane >> 4;
  const int lsw = (lane * 8) ^ (ko << 4);

  f32x4 acc[4][4];
#pragma unroll
  for (int m = 0; m < 4; ++m)
#pragma unroll
    for (int n = 0; n < 4; ++n) acc[m][n] = (f32x4)0.f;

  short8 ra[4], rb[4];
  auto LOADG = [&](int kt) {
#pragma unroll
    for (int i = 0; i < 4; ++i) {
      const int ch = tid + i * 256;
      const int row = ch >> 3, slotk = ch & 7;
      const int ar = min(m0 + row, Mch - 1);
      ra[i] = *(const short8*)&A[(size_t)ar * 768 + kt * 64 + slotk * 8];
      rb[i] = *(const short8*)&Bw[(size_t)(c0 + row) * 768 + kt * 64 + slotk * 8];
    }
  };
  auto WRITE = [&]() {
#pragma unroll
    for (int i = 0; i < 4; ++i) {
      const int ch = tid + i * 256;
      const int row = ch >> 3, slotk = ch & 7;
      const int s = slotk >> 2, sl = slotk & 3;
      const int off = (row >> 4) * 1024 + s * 512 +
                      ((sl * 128 + (row & 15) * 8) ^ (sl << 4));
      *(short8*)&As[off] = ra[i];
      *(short8*)&Bs[off] = rb[i];
    }
  };

  LOADG(0);
  for (int kt = 0; kt < 12; ++kt) {
    __syncthreads();
    WRITE();
    if (kt < 11) LOADG(kt + 1);
    __syncthreads();
#pragma unroll
    for (int s = 0; s < 2; ++s) {
      short8 af[4], bfr[4];
#pragma unroll
      for (int m = 0; m < 4; ++m)
        af[m] = *(const short8*)&As[((wr * 4 + m) * 2 + s) * 512 + lsw];
#pragma unroll
      for (int n = 0; n < 4; ++n)
        bfr[n] = *(const short8*)&Bs[((wc * 4 + n) * 2 + s) * 512 + lsw];
#pragma unroll
      for (int m = 0; m < 4; ++m)
#pragma unroll
        for (int n = 0; n < 4; ++n)
          acc[m][n] = __builtin_amdgcn_mfma_f32_16x16x32_bf16(af[m], bfr[n], acc[m][n], 0, 0, 0);
    }
  }

  __syncthreads();
  const int t = c0 / 768;
  const int hbase = (c0 % 768) >> 6;
  if (t < 2) {
#pragma unroll
    for (int n = 0; n < 4; ++n) {
      const int col = wc * 64 + n * 16 + fr;
      const float bv = bias[c0 + col];
#pragma unroll
      for (int m = 0; m < 4; ++m)
#pragma unroll
        for (int r = 0; r < 4; ++r) {
          const int row = wr * 64 + m * 16 + ko * 4 + r;
          SH[row * 136 + col] = f2bf(acc[m][n][r] + bv);
        }
    }
    __syncthreads();
    u16* dst = (t == 0) ? qb : kb;
    for (int it = tid; it < 2048; it += 256) {
      const int rt = it >> 4, half2 = (it >> 3) & 1, p = it & 7;
      const int mg = m0 + rt;
      if (mg < Mch) {
        const int bl = mg / N_, nt = mg - bl * N_;
        const short8 vv = *(const short8*)&SH[rt * 136 + half2 * 64 + p * 8];
        *(short8*)&dst[(((size_t)bl * H_ + hbase + half2) * N_ + nt) * 64 + p * 8] = vv;
      }
    }
  } else {
#pragma unroll
    for (int n = 0; n < 4; ++n) {
      const int col = wc * 64 + n * 16 + fr;
      const float bv = bias[c0 + col];
#pragma unroll
      for (int m = 0; m < 4; ++m)
#pragma unroll
        for (int r = 0; r < 4; ++r) {
          const int row = wr * 64 + m * 16 + ko * 4 + r;
          SH[col * 136 + row] = f2bf(acc[m][n][r] + bv);
        }
    }
    __syncthreads();
    for (int it = tid; it < 2048; it += 256) {
      const int ct = it >> 4, tc = it & 15;
      const int mg0 = m0 + tc * 8;
      if (mg0 < Mch) {
        const int bl = mg0 / N_, nt = mg0 - bl * N_;
        const int d = ct & 63, hh = hbase + (ct >> 6);
        const short8 vv = *(const short8*)&SH[ct * 136 + tc * 8];
        *(short8*)&vb[(((size_t)bl * H_ + hh) * 64 + d) * N_ + nt] = vv;
      }
    }
  }
}

// ------------------------------------------------------------------
// Proj GEMM, 2-term: out = Ah@(Bh+Bl)^T + bias (R14) — unchanged.
// ------------------------------------------------------------------
__global__ __launch_bounds__(256, 3) void gemm_proj(
    const u16* __restrict__ Ahg, const u16* __restrict__ Bhg,
    const u16* __restrict__ Blg, const float* __restrict__ bias,
    float* __restrict__ out) {
  __shared__ u16 Ah[8192], Bh[8192], Bl[8192];
  const int tid = threadIdx.x;
  const int swz = xcd_swz(blockIdx.x, gridDim.x);
  const int brow = swz / 6, bcol = swz - brow * 6;
  const int m0 = brow * 128, c0 = bcol * 128;
  const int lane = tid & 63, w = tid >> 6;
  const int wr = w >> 1, wc = w & 1;
  const int fr = lane & 15, ko = lane >> 4;
  const int lsw = (lane * 8) ^ (ko << 4);

  f32x4 acc[4][4];
#pragma unroll
  for (int m = 0; m < 4; ++m)
#pragma unroll
    for (int n = 0; n < 4; ++n) acc[m][n] = (f32x4)0.f;

  short8 rah[4], rbh[4], rbl[4];
  auto LOADG = [&](int kt) {
#pragma unroll
    for (int i = 0; i < 4; ++i) {
      const int ch = tid + i * 256;
      const int row = ch >> 3, slotk = ch & 7;
      const size_t aoff = (size_t)(m0 + row) * 768 + kt * 64 + slotk * 8;
      const size_t boff = (size_t)(c0 + row) * 768 + kt * 64 + slotk * 8;
      rah[i] = *(const short8*)&Ahg[aoff];
      rbh[i] = *(const short8*)&Bhg[boff];
      rbl[i] = *(const short8*)&Blg[boff];
    }
  };
  auto WRITE = [&]() {
#pragma unroll
    for (int i = 0; i < 4; ++i) {
      const int ch = tid + i * 256;
      const int row = ch >> 3, slotk = ch & 7;
      const int s = slotk >> 2, sl = slotk & 3;
      const int off = (row >> 4) * 1024 + s * 512 +
                      ((sl * 128 + (row & 15) * 8) ^ (sl << 4));
      *(short8*)&Ah[off] = rah[i];
      *(short8*)&Bh[off] = rbh[i];
      *(short8*)&Bl[off] = rbl[i];
    }
  };

  LOADG(0);
  for (int kt = 0; kt < 12; ++kt) {
    __syncthreads();
    WRITE();
    if (kt < 11) LOADG(kt + 1);
    __syncthreads();
#pragma unroll
    for (int s = 0; s < 2; ++s) {
      short8 ah[4], bh[4], bl[4];
#pragma unroll
      for (int m = 0; m < 4; ++m)
        ah[m] = *(const short8*)&Ah[((wr * 4 + m) * 2 + s) * 512 + lsw];
#pragma unroll
      for (int n = 0; n < 4; ++n) {
        const int off = ((wc * 4 + n) * 2 + s) * 512 + lsw;
        bh[n] = *(const short8*)&Bh[off];
        bl[n] = *(const short8*)&Bl[off];
      }
#pragma unroll
      for (int m = 0; m < 4; ++m)
#pragma unroll
        for (int n = 0; n < 4; ++n) {
          acc[m][n] = __builtin_amdgcn_mfma_f32_16x16x32_bf16(ah[m], bh[n], acc[m][n], 0, 0, 0);
          acc[m][n] = __builtin_amdgcn_mfma_f32_16x16x32_bf16(ah[m], bl[n], acc[m][n], 0, 0, 0);
        }
    }
  }
#pragma unroll
  for (int n = 0; n < 4; ++n) {
    const int col = c0 + wc * 64 + n * 16 + fr;
    const float bv = bias[col];
#pragma unroll
    for (int m = 0; m < 4; ++m) {
      const int mg = m0 + wr * 64 + m * 16 + ko * 4;
#pragma unroll
      for (int r = 0; r < 4; ++r) out[(size_t)(mg + r) * 768 + col] = acc[m][n][r] + bv;
    }
  }
}

// ------------------------------------------------------------------
// Agent pooling (scrambled reshape); rows 49..63 zeroed.
// ------------------------------------------------------------------
__global__ __launch_bounds__(256) void agent_pool(const u16* __restrict__ q,
                                                  u16* __restrict__ agent) {
  const int wid = threadIdx.x >> 6;
  const int lane = threadIdx.x & 63;
  const int row = blockIdx.x * 4 + wid;
  const int rem = row % (H_ * 64);
  const int b = row / (H_ * 64);
  const int h2 = rem / 64;
  const int a = rem % 64;
  if (a >= AG_) {
    agent[((size_t)b * H_ + h2) * 4096 + a * 64 + lane] = 0;
    return;
  }
  const int ap = a / 7, aq = a % 7;
  float s = 0.f;
#pragma unroll
  for (int i = 0; i < 4; ++i)
#pragma unroll
    for (int j = 0; j < 4; ++j) {
      const int g = (ap * 4 + i) * 336 + (aq * 4 + j) * 12 + h2;
      const int h = g / 784, n = g % 784;
      s += bf2f(q[(((size_t)b * H_ + h) * N_ + NMT_ + n) * HD_ + lane]);
    }
  agent[((size_t)b * H_ + h2) * 4096 + a * 64 + lane] = f2bf(s * 0.0625f);
}

// ------------------------------------------------------------------
// Flash attention — R16 measured-best version (vectorized Ps/Ss).
// ------------------------------------------------------------------
__global__ __launch_bounds__(256, 3) void flash_attn(
    const u16* __restrict__ Q, int q_bh_str, int q_base, int q_row_max, int q_valid,
    const u16* __restrict__ K, int k_bh_str, int k_row_max,
    const u16* __restrict__ Vt, int vt_bh_str, int vt_pitch, int vt_col_max,
    int n_keys, int nkt,
    u16* __restrict__ cch, int b0,
    u16* __restrict__ avT, int mode) {
  __shared__ u16 Qs[4096], Ks[4096], Vts[4096], Ps[4096];
  __shared__ float Ss[64][68];
  __shared__ float mS[64], lS[64], aS[64];

  const int tid = threadIdx.x, bh = blockIdx.x;
  const int q0 = q_base + blockIdx.y * 56;
  const int lane = tid & 63, w = tid >> 6;
  const int fr = lane & 15, ko = lane >> 4;

  const u16* Qb = Q + (size_t)bh * q_bh_str;
  const u16* Kb = K + (size_t)bh * k_bh_str;
  const u16* Vb = Vt + (size_t)bh * vt_bh_str;

#pragma unroll
  for (int i = 0; i < 2; ++i) {
    const int ch = tid + i * 256;
    const int row = ch >> 3, c8 = (ch & 7) << 3;
    const int qr = min(q0 + row, q_row_max);
    const short8 v = *(const short8*)&Qb[(size_t)qr * 64 + c8];
    *(short8*)&Qs[(row * 64 + c8) ^ ((row & 7) << 3)] = v;
  }
  if (tid < 64) { mS[tid] = NEGBIG_; lS[tid] = 0.f; aS[tid] = 0.f; }

  f32x4 oacc[4];
#pragma unroll
  for (int d = 0; d < 4; ++d) oacc[d] = (f32x4)0.f;

  for (int kt = 0; kt < nkt; ++kt) {
#pragma unroll
    for (int i = 0; i < 2; ++i) {
      const int ch = tid + i * 256;
      const int row = ch >> 3, c8 = (ch & 7) << 3;
      const int kr = min(kt * 64 + row, k_row_max);
      const short8 v = *(const short8*)&Kb[(size_t)kr * 64 + c8];
      *(short8*)&Ks[(row * 64 + c8) ^ ((row & 7) << 3)] = v;
    }
#pragma unroll
    for (int i = 0; i < 2; ++i) {
      const int ch = tid + i * 256;
      const int row = ch >> 3, c8 = (ch & 7) << 3;
      const int col8 = kt * 64 + c8;
      const u16* src = &Vb[(size_t)row * vt_pitch];
      short8 v;
      if (col8 + 8 <= vt_col_max) {
        v = *(const short8*)&src[col8];
      } else {
#pragma unroll
        for (int e = 0; e < 8; ++e) v[e] = (short)src[min(col8 + e, vt_col_max - 1)];
      }
      *(short8*)&Vts[(row * 64 + c8) ^ ((row & 7) << 3)] = v;
    }
    __syncthreads();

    // ---- S = Q K^T * 0.125 (MFMA), masked -> finite sentinel
    short8 aq[2];
#pragma unroll
    for (int s = 0; s < 2; ++s)
      aq[s] = *(const short8*)&Qs[((w * 16 + fr) * 64 + s * 32 + ko * 8) ^ ((fr & 7) << 3)];
#pragma unroll
    for (int j = 0; j < 4; ++j) {
      f32x4 sa = (f32x4)0.f;
#pragma unroll
      for (int s = 0; s < 2; ++s) {
        const short8 bk = *(const short8*)&Ks[((j * 16 + fr) * 64 + s * 32 + ko * 8) ^ ((fr & 7) << 3)];
        sa = __builtin_amdgcn_mfma_f32_16x16x32_bf16(aq[s], bk, sa, 0, 0, 0);
      }
      const int colg = kt * 64 + j * 16 + fr;
      const bool maskc = (colg >= n_keys);
#pragma unroll
      for (int r = 0; r < 4; ++r) {
        const int srow = w * 16 + ko * 4 + r;
        Ss[srow][j * 16 + fr] = maskc ? NEGBIG_ : sa[r] * 0.125f;
      }
    }
    __syncthreads();

    // ---- online softmax; vectorized Ss reads + Ps writes
    {
      const int r = tid >> 2, jj = tid & 3;
      float sv[16];
      float mx = NEGBIG_;
#pragma unroll
      for (int cc = 0; cc < 4; ++cc) {
        const f32x4 v4 = *(const f32x4*)&Ss[r][jj * 16 + cc * 4];
#pragma unroll
        for (int e = 0; e < 4; ++e) {
          sv[cc * 4 + e] = v4[e];
          mx = fmaxf(mx, v4[e]);
        }
      }
      mx = fmaxf(mx, __shfl_xor(mx, 1));
      mx = fmaxf(mx, __shfl_xor(mx, 2));
      const float mold = mS[r];
      const float mnew = fmaxf(mold, mx);
      float sum = 0.f;
      const int pbase = r * 64 + jj * 16;
      const int px = (r & 7) << 3;
#pragma unroll
      for (int hh = 0; hh < 2; ++hh) {
        short8 ph;
#pragma unroll
        for (int c = 0; c < 8; ++c) {
          const bool mk = (kt * 64 + jj * 16 + hh * 8 + c) >= n_keys;
          const float p = mk ? 0.f : __expf(sv[hh * 8 + c] - mnew);
          sum += p;
          ph[c] = (short)f2bf(p);
        }
        *(short8*)&Ps[(pbase + hh * 8) ^ px] = ph;
      }
      sum += __shfl_xor(sum, 1);
      sum += __shfl_xor(sum, 2);
      if (jj == 0) {
        const float alpha = __expf(mold - mnew);
        aS[r] = alpha;
        lS[r] = lS[r] * alpha + sum;
        mS[r] = mnew;
      }
    }
    __syncthreads();

    // ---- O = O*alpha + P V (MFMA)
    float al[4];
#pragma unroll
    for (int r = 0; r < 4; ++r) al[r] = aS[w * 16 + ko * 4 + r];
    short8 ap[2];
#pragma unroll
    for (int s = 0; s < 2; ++s)
      ap[s] = *(const short8*)&Ps[((w * 16 + fr) * 64 + s * 32 + ko * 8) ^ ((fr & 7) << 3)];
#pragma unroll
    for (int dj = 0; dj < 4; ++dj) {
      f32x4 o = oacc[dj];
#pragma unroll
      for (int r = 0; r < 4; ++r) o[r] *= al[r];
#pragma unroll
      for (int s = 0; s < 2; ++s) {
        const short8 bv = *(const short8*)&Vts[((dj * 16 + fr) * 64 + s * 32 + ko * 8) ^ ((fr & 7) << 3)];
        o = __builtin_amdgcn_mfma_f32_16x16x32_bf16(ap[s], bv, o, 0, 0, 0);
      }
      oacc[dj] = o;
    }
    __syncthreads();
  }

  float linv[4];
#pragma unroll
  for (int r = 0; r < 4; ++r) linv[r] = 1.f / fmaxf(lS[w * 16 + ko * 4 + r], 1e-30f);

  if (mode == 0) {
    const int b = bh / H_, h = bh % H_;
#pragma unroll
    for (int dj = 0; dj < 4; ++dj)
#pragma unroll
      for (int r = 0; r < 4; ++r) {
        const int rowl = w * 16 + ko * 4 + r;
        if (rowl < q_valid) {
          const size_t m = (size_t)(b0 + b) * N_ + q0 + rowl;
          cch[m * 768 + h * 64 + dj * 16 + fr] = f2bf(oacc[dj][r] * linv[r]);
        }
      }
  } else {
#pragma unroll
    for (int dj = 0; dj < 4; ++dj)
#pragma unroll
      for (int r = 0; r < 4; ++r) {
        const int a = w * 16 + ko * 4 + r;
        avT[(size_t)bh * 4096 + (dj * 16 + fr) * 64 + a] = f2bf(oacc[dj][r] * linv[r]);
      }
  }
}

// ------------------------------------------------------------------
extern "C" void kernel_launch(void* const* d_in, const int* in_sizes, int n_in,
                              void* d_out, int out_size, void* d_ws,
                              size_t ws_size, hipStream_t stream) {
  const float* x = (const float*)d_in[0];
  const float* qkv_w = (const float*)d_in[1];
  const float* qkv_b = (const float*)d_in[2];
  const float* proj_w = (const float*)d_in[3];
  const float* proj_b = (const float*)d_in[4];
  float* out = (float*)d_out;
  u16* ws = (u16*)d_ws;

  const size_t XBF = 28901376ull;
  const size_t QW = 2304ull * 768;
  const size_t PW = 768ull * 768;
  const size_t QKV1 = (size_t)H_ * N_ * HD_;
  const size_t AG1 = (size_t)H_ * 64 * 64;

  size_t o = 0;
  u16* xbf = ws + o; o += XBF;
  u16* qwh = ws + o; o += QW;
  u16* pwh = ws + o; o += PW;
  u16* pwl = ws + o; o += PW;
  u16* cch = ws + o; o += XBF;
  const size_t fixed_sh = o;
  const size_t per_sh = 3 * QKV1 + 2 * AG1;

  int cb = 1;
  const int cands[6] = {32, 16, 8, 4, 2, 1};
  for (int i = 0; i < 6; ++i)
    if ((fixed_sh + (size_t)cands[i] * per_sh) * 2 <= ws_size) { cb = cands[i]; break; }

  u16* qb = ws + o; o += cb * QKV1;
  u16* kb = ws + o; o += cb * QKV1;
  u16* vb = ws + o; o += cb * QKV1;
  u16* agent = ws + o; o += cb * AG1;
  u16* avT = ws + o; o += cb * AG1;

  split_all<<<3584, 256, 0, stream>>>(x, xbf, (int)(XBF / 4),
                                      qkv_w, qwh, (int)(QW / 4),
                                      proj_w, pwh, pwl, (int)(PW / 4));

  const int nch = B_ / cb;
  for (int chn = 0; chn < nch; ++chn) {
    const int b0 = chn * cb;
    const int Mch = cb * N_;
    const int nrow = (Mch + 127) / 128;
    gemm_qkv<<<dim3(nrow * 18), 256, 0, stream>>>(
        xbf + (size_t)b0 * N_ * 768, qwh, qkv_b, qb, kb, vb, Mch);
    agent_pool<<<dim3(cb * 192), 256, 0, stream>>>(qb, agent);
    // agent attention: 49 agents vs all 1176 keys -> avT (d-major)
    flash_attn<<<dim3(cb * H_, 1), 256, 0, stream>>>(
        agent, 4096, 0, 48, AG_, kb, N_ * HD_, N_ - 1,
        vb, N_ * HD_, N_, N_, N_, 19, nullptr, b0, avT, 1);
    // MT attention: 392 x 392
    flash_attn<<<dim3(cb * H_, 7), 256, 0, stream>>>(
        qb, N_ * HD_, 0, N_ - 1, 56, kb, N_ * HD_, N_ - 1,
        vb, N_ * HD_, N_, N_, NMT_, 7, cch, b0, nullptr, 0);
    // q_s attention: 784 x 49 agents
    flash_attn<<<dim3(cb * H_, 14), 256, 0, stream>>>(
        qb, N_ * HD_, NMT_, N_ - 1, 56, agent, 4096, 63,
        avT, 4096, 64, 64, AG_, 1, cch, b0, nullptr, 0);
  }
  gemm_proj<<<dim3(294 * 6), 256, 0, stream>>>(cch, pwh, pwl, proj_b, out);
}

// Round 19
// 509.482 us; speedup vs baseline: 1.0741x; 1.0195x over previous
//
#include <hip/hip_runtime.h>

typedef __attribute__((ext_vector_type(8))) short short8;
typedef __attribute__((ext_vector_type(4))) short short4v;
typedef __attribute__((ext_vector_type(4))) float f32x4;
typedef unsigned short u16;

#define B_    32
#define N_    1176
#define C_    768
#define H_    12
#define HD_   64
#define NMT_  392
#define AG_   49
#define NEGBIG_ (-1.0e4f)

__device__ __forceinline__ u16 f2bf(float f) {
  unsigned u = __float_as_uint(f);
  unsigned r = (u + 0x7fffu + ((u >> 16) & 1u)) >> 16;
  return (u16)r;
}
__device__ __forceinline__ float bf2f(u16 s) {
  return __uint_as_float(((unsigned)s) << 16);
}

// Bijective XCD-chunk swizzle (m204).
__device__ __forceinline__ int xcd_swz(int g, int nwg) {
  const int q = nwg >> 3, r = nwg & 7;
  const int xcd = g & 7, off = g >> 3;
  return (xcd < r ? xcd * (q + 1) : r * (q + 1) + (xcd - r) * q) + off;
}

// ------------------------------------------------------------------
// Combined fp32->bf16 split for x (hi), qkv_w (hi), proj_w (hi+lo).
// ------------------------------------------------------------------
__global__ __launch_bounds__(256) void split_all(
    const float* __restrict__ x, u16* __restrict__ xbf, int n4x,
    const float* __restrict__ qw, u16* __restrict__ qwh, int n4q,
    const float* __restrict__ pw, u16* __restrict__ pwh,
    u16* __restrict__ pwl, int n4p) {
  const int bid = blockIdx.x;
  const float* in;
  u16 *hi, *lo = nullptr;
  int n4, i0, nblk;
  if (bid < 2048) {
    in = x; hi = xbf; n4 = n4x; i0 = bid; nblk = 2048;
  } else if (bid < 3072) {
    in = qw; hi = qwh; n4 = n4q; i0 = bid - 2048; nblk = 1024;
  } else {
    in = pw; hi = pwh; lo = pwl; n4 = n4p; i0 = bid - 3072; nblk = 512;
  }
  int i = i0 * 256 + threadIdx.x;
  const int stride = nblk * 256;
  const bool dolo = (lo != nullptr);
  for (; i < n4; i += stride) {
    const float4 v = ((const float4*)in)[i];
    const float f[4] = {v.x, v.y, v.z, v.w};
    short4v h, l;
#pragma unroll
    for (int e = 0; e < 4; ++e) {
      u16 hb = f2bf(f[e]);
      h[e] = (short)hb;
      l[e] = (short)f2bf(f[e] - bf2f(hb));
    }
    ((short4v*)hi)[i] = h;
    if (dolo) ((short4v*)lo)[i] = l;
  }
}

// ------------------------------------------------------------------
// QKV GEMM R18b: 256x128 tile, 512 threads (8 waves, 2x4 of 64x64),
// BK=64, reg-staging + XOR-swizzled fragment LDS, col-group swizzle.
// Per-block MFMA per barrier pair doubles vs 128x128; B-traffic halves.
// Epilogue: two 128-row passes through the shared SH tile.
// ------------------------------------------------------------------
__global__ __launch_bounds__(512, 4) void gemm_qkv(
    const u16* __restrict__ A, const u16* __restrict__ Bw,
    const float* __restrict__ bias, u16* __restrict__ qb, u16* __restrict__ kb,
    u16* __restrict__ vb, int Mch) {
  __shared__ u16 SH[24576];  // As[0..16383] (256x64), Bs[16384..24575] (128x64); epi 128x136
  u16* As = SH;
  u16* Bs = SH + 16384;
  const int tid = threadIdx.x;
  const int swz = xcd_swz(blockIdx.x, gridDim.x);
  const int half = gridDim.x >> 1;          // nrow * 9
  const int cg = swz / half;
  const int rem = swz - cg * half;
  const int brow = rem / 9;
  const int bcol = cg * 9 + (rem - brow * 9);
  const int m0 = brow * 256, c0 = bcol * 128;
  const int lane = tid & 63, w = tid >> 6;
  const int wr = w >> 1, wc = w & 1;        // wr 0..3 (row 64-blk), wc 0..1 (col 64-blk)
  const int fr = lane & 15, ko = lane >> 4;
  const int lsw = (lane * 8) ^ (ko << 4);

  f32x4 acc[4][4];
#pragma unroll
  for (int m = 0; m < 4; ++m)
#pragma unroll
    for (int n = 0; n < 4; ++n) acc[m][n] = (f32x4)0.f;

  short8 ra[4], rb[2];
  auto LOADG = [&](int kt) {
#pragma unroll
    for (int i = 0; i < 4; ++i) {
      const int ch = tid + i * 512;          // 0..2047: row(256) x slotk(8)
      const int row = ch >> 3, slotk = ch & 7;
      const int ar = min(m0 + row, Mch - 1);
      ra[i] = *(const short8*)&A[(size_t)ar * 768 + kt * 64 + slotk * 8];
    }
#pragma unroll
    for (int i = 0; i < 2; ++i) {
      const int ch = tid + i * 512;          // 0..1023: row(128) x slotk(8)
      const int row = ch >> 3, slotk = ch & 7;
      rb[i] = *(const short8*)&Bw[(size_t)(c0 + row) * 768 + kt * 64 + slotk * 8];
    }
  };
  auto WRITE = [&]() {
#pragma unroll
    for (int i = 0; i < 4; ++i) {
      const int ch = tid + i * 512;
      const int row = ch >> 3, slotk = ch & 7;
      const int s = slotk >> 2, sl = slotk & 3;
      const int off = (row >> 4) * 1024 + s * 512 +
                      ((sl * 128 + (row & 15) * 8) ^ (sl << 4));
      *(short8*)&As[off] = ra[i];
    }
#pragma unroll
    for (int i = 0; i < 2; ++i) {
      const int ch = tid + i * 512;
      const int row = ch >> 3, slotk = ch & 7;
      const int s = slotk >> 2, sl = slotk & 3;
      const int off = (row >> 4) * 1024 + s * 512 +
                      ((sl * 128 + (row & 15) * 8) ^ (sl << 4));
      *(short8*)&Bs[off] = rb[i];
    }
  };

  LOADG(0);
  for (int kt = 0; kt < 12; ++kt) {
    __syncthreads();
    WRITE();
    if (kt < 11) LOADG(kt + 1);
    __syncthreads();
#pragma unroll
    for (int s = 0; s < 2; ++s) {
      short8 af[4], bfr[4];
#pragma unroll
      for (int m = 0; m < 4; ++m)
        af[m] = *(const short8*)&As[((wr * 4 + m) * 2 + s) * 512 + lsw];
#pragma unroll
      for (int n = 0; n < 4; ++n)
        bfr[n] = *(const short8*)&Bs[((wc * 4 + n) * 2 + s) * 512 + lsw];
#pragma unroll
      for (int m = 0; m < 4; ++m)
#pragma unroll
        for (int n = 0; n < 4; ++n)
          acc[m][n] = __builtin_amdgcn_mfma_f32_16x16x32_bf16(af[m], bfr[n], acc[m][n], 0, 0, 0);
    }
  }

  // ---- epilogue: two 128-row passes through SH (128x136 u16) ----
  const int t = c0 / 768;
  const int hbase = (c0 % 768) >> 6;
#pragma unroll
  for (int p2 = 0; p2 < 2; ++p2) {
    __syncthreads();  // SH free (prev compute / prev pass writes done)
    if ((wr >> 1) == p2) {
      const int lbase = (wr & 1) * 64;
      if (t < 2) {
#pragma unroll
        for (int n = 0; n < 4; ++n) {
          const int col = wc * 64 + n * 16 + fr;
          const float bv = bias[c0 + col];
#pragma unroll
          for (int m = 0; m < 4; ++m)
#pragma unroll
            for (int r = 0; r < 4; ++r) {
              const int lrow = lbase + m * 16 + ko * 4 + r;
              SH[lrow * 136 + col] = f2bf(acc[m][n][r] + bv);
            }
        }
      } else {
#pragma unroll
        for (int n = 0; n < 4; ++n) {
          const int col = wc * 64 + n * 16 + fr;
          const float bv = bias[c0 + col];
#pragma unroll
          for (int m = 0; m < 4; ++m)
#pragma unroll
            for (int r = 0; r < 4; ++r) {
              const int lrow = lbase + m * 16 + ko * 4 + r;
              SH[col * 136 + lrow] = f2bf(acc[m][n][r] + bv);
            }
        }
      }
    }
    __syncthreads();
    if (t < 2) {
      u16* dst = (t == 0) ? qb : kb;
#pragma unroll
      for (int it = 0; it < 4; ++it) {
        const int idx = tid + it * 512;
        const int rt = idx >> 4, half2 = (idx >> 3) & 1, p = idx & 7;
        const int mg = m0 + p2 * 128 + rt;
        if (mg < Mch) {
          const int bl = mg / N_, nt = mg - bl * N_;
          const short8 vv = *(const short8*)&SH[rt * 136 + half2 * 64 + p * 8];
          *(short8*)&dst[(((size_t)bl * H_ + hbase + half2) * N_ + nt) * 64 + p * 8] = vv;
        }
      }
    } else {
#pragma unroll
      for (int it = 0; it < 4; ++it) {
        const int idx = tid + it * 512;
        const int ct = idx >> 4, tc = idx & 15;
        const int mg0 = m0 + p2 * 128 + tc * 8;
        if (mg0 < Mch) {
          const int bl = mg0 / N_, nt = mg0 - bl * N_;
          const int d = ct & 63, hh = hbase + (ct >> 6);
          const short8 vv = *(const short8*)&SH[ct * 136 + tc * 8];
          *(short8*)&vb[(((size_t)bl * H_ + hh) * 64 + d) * N_ + nt] = vv;
        }
      }
    }
  }
}

// ------------------------------------------------------------------
// Proj GEMM, 2-term: out = Ah@(Bh+Bl)^T + bias (R14) — unchanged.
// ------------------------------------------------------------------
__global__ __launch_bounds__(256, 3) void gemm_proj(
    const u16* __restrict__ Ahg, const u16* __restrict__ Bhg,
    const u16* __restrict__ Blg, const float* __restrict__ bias,
    float* __restrict__ out) {
  __shared__ u16 Ah[8192], Bh[8192], Bl[8192];
  const int tid = threadIdx.x;
  const int swz = xcd_swz(blockIdx.x, gridDim.x);
  const int brow = swz / 6, bcol = swz - brow * 6;
  const int m0 = brow * 128, c0 = bcol * 128;
  const int lane = tid & 63, w = tid >> 6;
  const int wr = w >> 1, wc = w & 1;
  const int fr = lane & 15, ko = lane >> 4;
  const int lsw = (lane * 8) ^ (ko << 4);

  f32x4 acc[4][4];
#pragma unroll
  for (int m = 0; m < 4; ++m)
#pragma unroll
    for (int n = 0; n < 4; ++n) acc[m][n] = (f32x4)0.f;

  short8 rah[4], rbh[4], rbl[4];
  auto LOADG = [&](int kt) {
#pragma unroll
    for (int i = 0; i < 4; ++i) {
      const int ch = tid + i * 256;
      const int row = ch >> 3, slotk = ch & 7;
      const size_t aoff = (size_t)(m0 + row) * 768 + kt * 64 + slotk * 8;
      const size_t boff = (size_t)(c0 + row) * 768 + kt * 64 + slotk * 8;
      rah[i] = *(const short8*)&Ahg[aoff];
      rbh[i] = *(const short8*)&Bhg[boff];
      rbl[i] = *(const short8*)&Blg[boff];
    }
  };
  auto WRITE = [&]() {
#pragma unroll
    for (int i = 0; i < 4; ++i) {
      const int ch = tid + i * 256;
      const int row = ch >> 3, slotk = ch & 7;
      const int s = slotk >> 2, sl = slotk & 3;
      const int off = (row >> 4) * 1024 + s * 512 +
                      ((sl * 128 + (row & 15) * 8) ^ (sl << 4));
      *(short8*)&Ah[off] = rah[i];
      *(short8*)&Bh[off] = rbh[i];
      *(short8*)&Bl[off] = rbl[i];
    }
  };

  LOADG(0);
  for (int kt = 0; kt < 12; ++kt) {
    __syncthreads();
    WRITE();
    if (kt < 11) LOADG(kt + 1);
    __syncthreads();
#pragma unroll
    for (int s = 0; s < 2; ++s) {
      short8 ah[4], bh[4], bl[4];
#pragma unroll
      for (int m = 0; m < 4; ++m)
        ah[m] = *(const short8*)&Ah[((wr * 4 + m) * 2 + s) * 512 + lsw];
#pragma unroll
      for (int n = 0; n < 4; ++n) {
        const int off = ((wc * 4 + n) * 2 + s) * 512 + lsw;
        bh[n] = *(const short8*)&Bh[off];
        bl[n] = *(const short8*)&Bl[off];
      }
#pragma unroll
      for (int m = 0; m < 4; ++m)
#pragma unroll
        for (int n = 0; n < 4; ++n) {
          acc[m][n] = __builtin_amdgcn_mfma_f32_16x16x32_bf16(ah[m], bh[n], acc[m][n], 0, 0, 0);
          acc[m][n] = __builtin_amdgcn_mfma_f32_16x16x32_bf16(ah[m], bl[n], acc[m][n], 0, 0, 0);
        }
    }
  }
#pragma unroll
  for (int n = 0; n < 4; ++n) {
    const int col = c0 + wc * 64 + n * 16 + fr;
    const float bv = bias[col];
#pragma unroll
    for (int m = 0; m < 4; ++m) {
      const int mg = m0 + wr * 64 + m * 16 + ko * 4;
#pragma unroll
      for (int r = 0; r < 4; ++r) out[(size_t)(mg + r) * 768 + col] = acc[m][n][r] + bv;
    }
  }
}

// ------------------------------------------------------------------
// Agent pooling (scrambled reshape); rows 49..63 zeroed.
// ------------------------------------------------------------------
__global__ __launch_bounds__(256) void agent_pool(const u16* __restrict__ q,
                                                  u16* __restrict__ agent) {
  const int wid = threadIdx.x >> 6;
  const int lane = threadIdx.x & 63;
  const int row = blockIdx.x * 4 + wid;
  const int rem = row % (H_ * 64);
  const int b = row / (H_ * 64);
  const int h2 = rem / 64;
  const int a = rem % 64;
  if (a >= AG_) {
    agent[((size_t)b * H_ + h2) * 4096 + a * 64 + lane] = 0;
    return;
  }
  const int ap = a / 7, aq = a % 7;
  float s = 0.f;
#pragma unroll
  for (int i = 0; i < 4; ++i)
#pragma unroll
    for (int j = 0; j < 4; ++j) {
      const int g = (ap * 4 + i) * 336 + (aq * 4 + j) * 12 + h2;
      const int h = g / 784, n = g % 784;
      s += bf2f(q[(((size_t)b * H_ + h) * N_ + NMT_ + n) * HD_ + lane]);
    }
  agent[((size_t)b * H_ + h2) * 4096 + a * 64 + lane] = f2bf(s * 0.0625f);
}

// ------------------------------------------------------------------
// Flash attention — R16 measured-best version (vectorized Ps/Ss).
// ------------------------------------------------------------------
__global__ __launch_bounds__(256, 3) void flash_attn(
    const u16* __restrict__ Q, int q_bh_str, int q_base, int q_row_max, int q_valid,
    const u16* __restrict__ K, int k_bh_str, int k_row_max,
    const u16* __restrict__ Vt, int vt_bh_str, int vt_pitch, int vt_col_max,
    int n_keys, int nkt,
    u16* __restrict__ cch, int b0,
    u16* __restrict__ avT, int mode) {
  __shared__ u16 Qs[4096], Ks[4096], Vts[4096], Ps[4096];
  __shared__ float Ss[64][68];
  __shared__ float mS[64], lS[64], aS[64];

  const int tid = threadIdx.x, bh = blockIdx.x;
  const int q0 = q_base + blockIdx.y * 56;
  const int lane = tid & 63, w = tid >> 6;
  const int fr = lane & 15, ko = lane >> 4;

  const u16* Qb = Q + (size_t)bh * q_bh_str;
  const u16* Kb = K + (size_t)bh * k_bh_str;
  const u16* Vb = Vt + (size_t)bh * vt_bh_str;

#pragma unroll
  for (int i = 0; i < 2; ++i) {
    const int ch = tid + i * 256;
    const int row = ch >> 3, c8 = (ch & 7) << 3;
    const int qr = min(q0 + row, q_row_max);
    const short8 v = *(const short8*)&Qb[(size_t)qr * 64 + c8];
    *(short8*)&Qs[(row * 64 + c8) ^ ((row & 7) << 3)] = v;
  }
  if (tid < 64) { mS[tid] = NEGBIG_; lS[tid] = 0.f; aS[tid] = 0.f; }

  f32x4 oacc[4];
#pragma unroll
  for (int d = 0; d < 4; ++d) oacc[d] = (f32x4)0.f;

  for (int kt = 0; kt < nkt; ++kt) {
#pragma unroll
    for (int i = 0; i < 2; ++i) {
      const int ch = tid + i * 256;
      const int row = ch >> 3, c8 = (ch & 7) << 3;
      const int kr = min(kt * 64 + row, k_row_max);
      const short8 v = *(const short8*)&Kb[(size_t)kr * 64 + c8];
      *(short8*)&Ks[(row * 64 + c8) ^ ((row & 7) << 3)] = v;
    }
#pragma unroll
    for (int i = 0; i < 2; ++i) {
      const int ch = tid + i * 256;
      const int row = ch >> 3, c8 = (ch & 7) << 3;
      const int col8 = kt * 64 + c8;
      const u16* src = &Vb[(size_t)row * vt_pitch];
      short8 v;
      if (col8 + 8 <= vt_col_max) {
        v = *(const short8*)&src[col8];
      } else {
#pragma unroll
        for (int e = 0; e < 8; ++e) v[e] = (short)src[min(col8 + e, vt_col_max - 1)];
      }
      *(short8*)&Vts[(row * 64 + c8) ^ ((row & 7) << 3)] = v;
    }
    __syncthreads();

    // ---- S = Q K^T * 0.125 (MFMA), masked -> finite sentinel
    short8 aq[2];
#pragma unroll
    for (int s = 0; s < 2; ++s)
      aq[s] = *(const short8*)&Qs[((w * 16 + fr) * 64 + s * 32 + ko * 8) ^ ((fr & 7) << 3)];
#pragma unroll
    for (int j = 0; j < 4; ++j) {
      f32x4 sa = (f32x4)0.f;
#pragma unroll
      for (int s = 0; s < 2; ++s) {
        const short8 bk = *(const short8*)&Ks[((j * 16 + fr) * 64 + s * 32 + ko * 8) ^ ((fr & 7) << 3)];
        sa = __builtin_amdgcn_mfma_f32_16x16x32_bf16(aq[s], bk, sa, 0, 0, 0);
      }
      const int colg = kt * 64 + j * 16 + fr;
      const bool maskc = (colg >= n_keys);
#pragma unroll
      for (int r = 0; r < 4; ++r) {
        const int srow = w * 16 + ko * 4 + r;
        Ss[srow][j * 16 + fr] = maskc ? NEGBIG_ : sa[r] * 0.125f;
      }
    }
    __syncthreads();

    // ---- online softmax; vectorized Ss reads + Ps writes
    {
      const int r = tid >> 2, jj = tid & 3;
      float sv[16];
      float mx = NEGBIG_;
#pragma unroll
      for (int cc = 0; cc < 4; ++cc) {
        const f32x4 v4 = *(const f32x4*)&Ss[r][jj * 16 + cc * 4];
#pragma unroll
        for (int e = 0; e < 4; ++e) {
          sv[cc * 4 + e] = v4[e];
          mx = fmaxf(mx, v4[e]);
        }
      }
      mx = fmaxf(mx, __shfl_xor(mx, 1));
      mx = fmaxf(mx, __shfl_xor(mx, 2));
      const float mold = mS[r];
      const float mnew = fmaxf(mold, mx);
      float sum = 0.f;
      const int pbase = r * 64 + jj * 16;
      const int px = (r & 7) << 3;
#pragma unroll
      for (int hh = 0; hh < 2; ++hh) {
        short8 ph;
#pragma unroll
        for (int c = 0; c < 8; ++c) {
          const bool mk = (kt * 64 + jj * 16 + hh * 8 + c) >= n_keys;
          const float p = mk ? 0.f : __expf(sv[hh * 8 + c] - mnew);
          sum += p;
          ph[c] = (short)f2bf(p);
        }
        *(short8*)&Ps[(pbase + hh * 8) ^ px] = ph;
      }
      sum += __shfl_xor(sum, 1);
      sum += __shfl_xor(sum, 2);
      if (jj == 0) {
        const float alpha = __expf(mold - mnew);
        aS[r] = alpha;
        lS[r] = lS[r] * alpha + sum;
        mS[r] = mnew;
      }
    }
    __syncthreads();

    // ---- O = O*alpha + P V (MFMA)
    float al[4];
#pragma unroll
    for (int r = 0; r < 4; ++r) al[r] = aS[w * 16 + ko * 4 + r];
    short8 ap[2];
#pragma unroll
    for (int s = 0; s < 2; ++s)
      ap[s] = *(const short8*)&Ps[((w * 16 + fr) * 64 + s * 32 + ko * 8) ^ ((fr & 7) << 3)];
#pragma unroll
    for (int dj = 0; dj < 4; ++dj) {
      f32x4 o = oacc[dj];
#pragma unroll
      for (int r = 0; r < 4; ++r) o[r] *= al[r];
#pragma unroll
      for (int s = 0; s < 2; ++s) {
        const short8 bv = *(const short8*)&Vts[((dj * 16 + fr) * 64 + s * 32 + ko * 8) ^ ((fr & 7) << 3)];
        o = __builtin_amdgcn_mfma_f32_16x16x32_bf16(ap[s], bv, o, 0, 0, 0);
      }
      oacc[dj] = o;
    }
    __syncthreads();
  }

  float linv[4];
#pragma unroll
  for (int r = 0; r < 4; ++r) linv[r] = 1.f / fmaxf(lS[w * 16 + ko * 4 + r], 1e-30f);

  if (mode == 0) {
    const int b = bh / H_, h = bh % H_;
#pragma unroll
    for (int dj = 0; dj < 4; ++dj)
#pragma unroll
      for (int r = 0; r < 4; ++r) {
        const int rowl = w * 16 + ko * 4 + r;
        if (rowl < q_valid) {
          const size_t m = (size_t)(b0 + b) * N_ + q0 + rowl;
          cch[m * 768 + h * 64 + dj * 16 + fr] = f2bf(oacc[dj][r] * linv[r]);
        }
      }
  } else {
#pragma unroll
    for (int dj = 0; dj < 4; ++dj)
#pragma unroll
      for (int r = 0; r < 4; ++r) {
        const int a = w * 16 + ko * 4 + r;
        avT[(size_t)bh * 4096 + (dj * 16 + fr) * 64 + a] = f2bf(oacc[dj][r] * linv[r]);
      }
  }
}

// ------------------------------------------------------------------
extern "C" void kernel_launch(void* const* d_in, const int* in_sizes, int n_in,
                              void* d_out, int out_size, void* d_ws,
                              size_t ws_size, hipStream_t stream) {
  const float* x = (const float*)d_in[0];
  const float* qkv_w = (const float*)d_in[1];
  const float* qkv_b = (const float*)d_in[2];
  const float* proj_w = (const float*)d_in[3];
  const float* proj_b = (const float*)d_in[4];
  float* out = (float*)d_out;
  u16* ws = (u16*)d_ws;

  const size_t XBF = 28901376ull;
  const size_t QW = 2304ull * 768;
  const size_t PW = 768ull * 768;
  const size_t QKV1 = (size_t)H_ * N_ * HD_;
  const size_t AG1 = (size_t)H_ * 64 * 64;

  size_t o = 0;
  u16* xbf = ws + o; o += XBF;
  u16* qwh = ws + o; o += QW;
  u16* pwh = ws + o; o += PW;
  u16* pwl = ws + o; o += PW;
  u16* cch = ws + o; o += XBF;
  const size_t fixed_sh = o;
  const size_t per_sh = 3 * QKV1 + 2 * AG1;

  int cb = 1;
  const int cands[6] = {32, 16, 8, 4, 2, 1};
  for (int i = 0; i < 6; ++i)
    if ((fixed_sh + (size_t)cands[i] * per_sh) * 2 <= ws_size) { cb = cands[i]; break; }

  u16* qb = ws + o; o += cb * QKV1;
  u16* kb = ws + o; o += cb * QKV1;
  u16* vb = ws + o; o += cb * QKV1;
  u16* agent = ws + o; o += cb * AG1;
  u16* avT = ws + o; o += cb * AG1;

  split_all<<<3584, 256, 0, stream>>>(x, xbf, (int)(XBF / 4),
                                      qkv_w, qwh, (int)(QW / 4),
                                      proj_w, pwh, pwl, (int)(PW / 4));

  const int nch = B_ / cb;
  for (int chn = 0; chn < nch; ++chn) {
    const int b0 = chn * cb;
    const int Mch = cb * N_;
    const int nrow = (Mch + 255) / 256;
    gemm_qkv<<<dim3(nrow * 18), 512, 0, stream>>>(
        xbf + (size_t)b0 * N_ * 768, qwh, qkv_b, qb, kb, vb, Mch);
    agent_pool<<<dim3(cb * 192), 256, 0, stream>>>(qb, agent);
    // agent attention: 49 agents vs all 1176 keys -> avT (d-major)
    flash_attn<<<dim3(cb * H_, 1), 256, 0, stream>>>(
        agent, 4096, 0, 48, AG_, kb, N_ * HD_, N_ - 1,
        vb, N_ * HD_, N_, N_, N_, 19, nullptr, b0, avT, 1);
    // MT attention: 392 x 392
    flash_attn<<<dim3(cb * H_, 7), 256, 0, stream>>>(
        qb, N_ * HD_, 0, N_ - 1, 56, kb, N_ * HD_, N_ - 1,
        vb, N_ * HD_, N_, N_, NMT_, 7, cch, b0, nullptr, 0);
    // q_s attention: 784 x 49 agents
    flash_attn<<<dim3(cb * H_, 14), 256, 0, stream>>>(
        qb, N_ * HD_, NMT_, N_ - 1, 56, agent, 4096, 63,
        avT, 4096, 64, 64, AG_, 1, cch, b0, nullptr, 0);
  }
  gemm_proj<<<dim3(294 * 6), 256, 0, stream>>>(cch, pwh, pwl, proj_b, out);
}

// Round 20
// 471.347 us; speedup vs baseline: 1.1610x; 1.0809x over previous
//
#include <hip/hip_runtime.h>

typedef __attribute__((ext_vector_type(8))) short short8;
typedef __attribute__((ext_vector_type(4))) short short4v;
typedef __attribute__((ext_vector_type(4))) float f32x4;
typedef unsigned short u16;

#define B_    32
#define N_    1176
#define C_    768
#define H_    12
#define HD_   64
#define NMT_  392
#define AG_   49
#define NEGBIG_ (-1.0e4f)

__device__ __forceinline__ u16 f2bf(float f) {
  unsigned u = __float_as_uint(f);
  unsigned r = (u + 0x7fffu + ((u >> 16) & 1u)) >> 16;
  return (u16)r;
}
__device__ __forceinline__ float bf2f(u16 s) {
  return __uint_as_float(((unsigned)s) << 16);
}

// Bijective XCD-chunk swizzle (m204).
__device__ __forceinline__ int xcd_swz(int g, int nwg) {
  const int q = nwg >> 3, r = nwg & 7;
  const int xcd = g & 7, off = g >> 3;
  return (xcd < r ? xcd * (q + 1) : r * (q + 1) + (xcd - r) * q) + off;
}

// ------------------------------------------------------------------
// Combined fp32->bf16 split for x (hi), qkv_w (hi), proj_w (hi+lo).
// ------------------------------------------------------------------
__global__ __launch_bounds__(256) void split_all(
    const float* __restrict__ x, u16* __restrict__ xbf, int n4x,
    const float* __restrict__ qw, u16* __restrict__ qwh, int n4q,
    const float* __restrict__ pw, u16* __restrict__ pwh,
    u16* __restrict__ pwl, int n4p) {
  const int bid = blockIdx.x;
  const float* in;
  u16 *hi, *lo = nullptr;
  int n4, i0, nblk;
  if (bid < 2048) {
    in = x; hi = xbf; n4 = n4x; i0 = bid; nblk = 2048;
  } else if (bid < 3072) {
    in = qw; hi = qwh; n4 = n4q; i0 = bid - 2048; nblk = 1024;
  } else {
    in = pw; hi = pwh; lo = pwl; n4 = n4p; i0 = bid - 3072; nblk = 512;
  }
  int i = i0 * 256 + threadIdx.x;
  const int stride = nblk * 256;
  const bool dolo = (lo != nullptr);
  for (; i < n4; i += stride) {
    const float4 v = ((const float4*)in)[i];
    const float f[4] = {v.x, v.y, v.z, v.w};
    short4v h, l;
#pragma unroll
    for (int e = 0; e < 4; ++e) {
      u16 hb = f2bf(f[e]);
      h[e] = (short)hb;
      l[e] = (short)f2bf(f[e] - bf2f(hb));
    }
    ((short4v*)hi)[i] = h;
    if (dolo) ((short4v*)lo)[i] = l;
  }
}

// ------------------------------------------------------------------
// QKV GEMM R19: 256x128 tile, 512 threads, BK=64 — unchanged.
// ------------------------------------------------------------------
__global__ __launch_bounds__(512, 4) void gemm_qkv(
    const u16* __restrict__ A, const u16* __restrict__ Bw,
    const float* __restrict__ bias, u16* __restrict__ qb, u16* __restrict__ kb,
    u16* __restrict__ vb, int Mch) {
  __shared__ u16 SH[24576];
  u16* As = SH;
  u16* Bs = SH + 16384;
  const int tid = threadIdx.x;
  const int swz = xcd_swz(blockIdx.x, gridDim.x);
  const int half = gridDim.x >> 1;
  const int cg = swz / half;
  const int rem = swz - cg * half;
  const int brow = rem / 9;
  const int bcol = cg * 9 + (rem - brow * 9);
  const int m0 = brow * 256, c0 = bcol * 128;
  const int lane = tid & 63, w = tid >> 6;
  const int wr = w >> 1, wc = w & 1;
  const int fr = lane & 15, ko = lane >> 4;
  const int lsw = (lane * 8) ^ (ko << 4);

  f32x4 acc[4][4];
#pragma unroll
  for (int m = 0; m < 4; ++m)
#pragma unroll
    for (int n = 0; n < 4; ++n) acc[m][n] = (f32x4)0.f;

  short8 ra[4], rb[2];
  auto LOADG = [&](int kt) {
#pragma unroll
    for (int i = 0; i < 4; ++i) {
      const int ch = tid + i * 512;
      const int row = ch >> 3, slotk = ch & 7;
      const int ar = min(m0 + row, Mch - 1);
      ra[i] = *(const short8*)&A[(size_t)ar * 768 + kt * 64 + slotk * 8];
    }
#pragma unroll
    for (int i = 0; i < 2; ++i) {
      const int ch = tid + i * 512;
      const int row = ch >> 3, slotk = ch & 7;
      rb[i] = *(const short8*)&Bw[(size_t)(c0 + row) * 768 + kt * 64 + slotk * 8];
    }
  };
  auto WRITE = [&]() {
#pragma unroll
    for (int i = 0; i < 4; ++i) {
      const int ch = tid + i * 512;
      const int row = ch >> 3, slotk = ch & 7;
      const int s = slotk >> 2, sl = slotk & 3;
      const int off = (row >> 4) * 1024 + s * 512 +
                      ((sl * 128 + (row & 15) * 8) ^ (sl << 4));
      *(short8*)&As[off] = ra[i];
    }
#pragma unroll
    for (int i = 0; i < 2; ++i) {
      const int ch = tid + i * 512;
      const int row = ch >> 3, slotk = ch & 7;
      const int s = slotk >> 2, sl = slotk & 3;
      const int off = (row >> 4) * 1024 + s * 512 +
                      ((sl * 128 + (row & 15) * 8) ^ (sl << 4));
      *(short8*)&Bs[off] = rb[i];
    }
  };

  LOADG(0);
  for (int kt = 0; kt < 12; ++kt) {
    __syncthreads();
    WRITE();
    if (kt < 11) LOADG(kt + 1);
    __syncthreads();
#pragma unroll
    for (int s = 0; s < 2; ++s) {
      short8 af[4], bfr[4];
#pragma unroll
      for (int m = 0; m < 4; ++m)
        af[m] = *(const short8*)&As[((wr * 4 + m) * 2 + s) * 512 + lsw];
#pragma unroll
      for (int n = 0; n < 4; ++n)
        bfr[n] = *(const short8*)&Bs[((wc * 4 + n) * 2 + s) * 512 + lsw];
#pragma unroll
      for (int m = 0; m < 4; ++m)
#pragma unroll
        for (int n = 0; n < 4; ++n)
          acc[m][n] = __builtin_amdgcn_mfma_f32_16x16x32_bf16(af[m], bfr[n], acc[m][n], 0, 0, 0);
    }
  }

  const int t = c0 / 768;
  const int hbase = (c0 % 768) >> 6;
#pragma unroll
  for (int p2 = 0; p2 < 2; ++p2) {
    __syncthreads();
    if ((wr >> 1) == p2) {
      const int lbase = (wr & 1) * 64;
      if (t < 2) {
#pragma unroll
        for (int n = 0; n < 4; ++n) {
          const int col = wc * 64 + n * 16 + fr;
          const float bv = bias[c0 + col];
#pragma unroll
          for (int m = 0; m < 4; ++m)
#pragma unroll
            for (int r = 0; r < 4; ++r) {
              const int lrow = lbase + m * 16 + ko * 4 + r;
              SH[lrow * 136 + col] = f2bf(acc[m][n][r] + bv);
            }
        }
      } else {
#pragma unroll
        for (int n = 0; n < 4; ++n) {
          const int col = wc * 64 + n * 16 + fr;
          const float bv = bias[c0 + col];
#pragma unroll
          for (int m = 0; m < 4; ++m)
#pragma unroll
            for (int r = 0; r < 4; ++r) {
              const int lrow = lbase + m * 16 + ko * 4 + r;
              SH[col * 136 + lrow] = f2bf(acc[m][n][r] + bv);
            }
        }
      }
    }
    __syncthreads();
    if (t < 2) {
      u16* dst = (t == 0) ? qb : kb;
#pragma unroll
      for (int it = 0; it < 4; ++it) {
        const int idx = tid + it * 512;
        const int rt = idx >> 4, half2 = (idx >> 3) & 1, p = idx & 7;
        const int mg = m0 + p2 * 128 + rt;
        if (mg < Mch) {
          const int bl = mg / N_, nt = mg - bl * N_;
          const short8 vv = *(const short8*)&SH[rt * 136 + half2 * 64 + p * 8];
          *(short8*)&dst[(((size_t)bl * H_ + hbase + half2) * N_ + nt) * 64 + p * 8] = vv;
        }
      }
    } else {
#pragma unroll
      for (int it = 0; it < 4; ++it) {
        const int idx = tid + it * 512;
        const int ct = idx >> 4, tc = idx & 15;
        const int mg0 = m0 + p2 * 128 + tc * 8;
        if (mg0 < Mch) {
          const int bl = mg0 / N_, nt = mg0 - bl * N_;
          const int d = ct & 63, hh = hbase + (ct >> 6);
          const short8 vv = *(const short8*)&SH[ct * 136 + tc * 8];
          *(short8*)&vb[(((size_t)bl * H_ + hh) * 64 + d) * N_ + nt] = vv;
        }
      }
    }
  }
}

// ------------------------------------------------------------------
// Proj GEMM R19b: 256x128 tile, 512 threads (8 waves), BK=64, 2-term
// out = Ah@(Bh+Bl)^T + bias. LDS 64KB (Ah 32K + Bh 16K + Bl 16K),
// 2 blocks/CU. Grid 147x6 = 882 (M=37632 divides 256 exactly).
// ------------------------------------------------------------------
__global__ __launch_bounds__(512, 2) void gemm_proj(
    const u16* __restrict__ Ahg, const u16* __restrict__ Bhg,
    const u16* __restrict__ Blg, const float* __restrict__ bias,
    float* __restrict__ out) {
  __shared__ u16 Ah[16384], Bh[8192], Bl[8192];
  const int tid = threadIdx.x;
  const int swz = xcd_swz(blockIdx.x, gridDim.x);
  const int brow = swz / 6, bcol = swz - brow * 6;
  const int m0 = brow * 256, c0 = bcol * 128;
  const int lane = tid & 63, w = tid >> 6;
  const int wr = w >> 1, wc = w & 1;
  const int fr = lane & 15, ko = lane >> 4;
  const int lsw = (lane * 8) ^ (ko << 4);

  f32x4 acc[4][4];
#pragma unroll
  for (int m = 0; m < 4; ++m)
#pragma unroll
    for (int n = 0; n < 4; ++n) acc[m][n] = (f32x4)0.f;

  short8 ra[4], rbh[2], rbl[2];
  auto LOADG = [&](int kt) {
#pragma unroll
    for (int i = 0; i < 4; ++i) {
      const int ch = tid + i * 512;
      const int row = ch >> 3, slotk = ch & 7;
      ra[i] = *(const short8*)&Ahg[(size_t)(m0 + row) * 768 + kt * 64 + slotk * 8];
    }
#pragma unroll
    for (int i = 0; i < 2; ++i) {
      const int ch = tid + i * 512;
      const int row = ch >> 3, slotk = ch & 7;
      const size_t boff = (size_t)(c0 + row) * 768 + kt * 64 + slotk * 8;
      rbh[i] = *(const short8*)&Bhg[boff];
      rbl[i] = *(const short8*)&Blg[boff];
    }
  };
  auto WRITE = [&]() {
#pragma unroll
    for (int i = 0; i < 4; ++i) {
      const int ch = tid + i * 512;
      const int row = ch >> 3, slotk = ch & 7;
      const int s = slotk >> 2, sl = slotk & 3;
      const int off = (row >> 4) * 1024 + s * 512 +
                      ((sl * 128 + (row & 15) * 8) ^ (sl << 4));
      *(short8*)&Ah[off] = ra[i];
    }
#pragma unroll
    for (int i = 0; i < 2; ++i) {
      const int ch = tid + i * 512;
      const int row = ch >> 3, slotk = ch & 7;
      const int s = slotk >> 2, sl = slotk & 3;
      const int off = (row >> 4) * 1024 + s * 512 +
                      ((sl * 128 + (row & 15) * 8) ^ (sl << 4));
      *(short8*)&Bh[off] = rbh[i];
      *(short8*)&Bl[off] = rbl[i];
    }
  };

  LOADG(0);
  for (int kt = 0; kt < 12; ++kt) {
    __syncthreads();
    WRITE();
    if (kt < 11) LOADG(kt + 1);
    __syncthreads();
#pragma unroll
    for (int s = 0; s < 2; ++s) {
      short8 af[4], bh[4], bl[4];
#pragma unroll
      for (int m = 0; m < 4; ++m)
        af[m] = *(const short8*)&Ah[((wr * 4 + m) * 2 + s) * 512 + lsw];
#pragma unroll
      for (int n = 0; n < 4; ++n) {
        const int off = ((wc * 4 + n) * 2 + s) * 512 + lsw;
        bh[n] = *(const short8*)&Bh[off];
        bl[n] = *(const short8*)&Bl[off];
      }
#pragma unroll
      for (int m = 0; m < 4; ++m)
#pragma unroll
        for (int n = 0; n < 4; ++n) {
          acc[m][n] = __builtin_amdgcn_mfma_f32_16x16x32_bf16(af[m], bh[n], acc[m][n], 0, 0, 0);
          acc[m][n] = __builtin_amdgcn_mfma_f32_16x16x32_bf16(af[m], bl[n], acc[m][n], 0, 0, 0);
        }
    }
  }
#pragma unroll
  for (int n = 0; n < 4; ++n) {
    const int col = c0 + wc * 64 + n * 16 + fr;
    const float bv = bias[col];
#pragma unroll
    for (int m = 0; m < 4; ++m) {
      const int mg = m0 + wr * 64 + m * 16 + ko * 4;
#pragma unroll
      for (int r = 0; r < 4; ++r) out[(size_t)(mg + r) * 768 + col] = acc[m][n][r] + bv;
    }
  }
}

// ------------------------------------------------------------------
// Agent pooling (scrambled reshape); rows 49..63 zeroed.
// ------------------------------------------------------------------
__global__ __launch_bounds__(256) void agent_pool(const u16* __restrict__ q,
                                                  u16* __restrict__ agent) {
  const int wid = threadIdx.x >> 6;
  const int lane = threadIdx.x & 63;
  const int row = blockIdx.x * 4 + wid;
  const int rem = row % (H_ * 64);
  const int b = row / (H_ * 64);
  const int h2 = rem / 64;
  const int a = rem % 64;
  if (a >= AG_) {
    agent[((size_t)b * H_ + h2) * 4096 + a * 64 + lane] = 0;
    return;
  }
  const int ap = a / 7, aq = a % 7;
  float s = 0.f;
#pragma unroll
  for (int i = 0; i < 4; ++i)
#pragma unroll
    for (int j = 0; j < 4; ++j) {
      const int g = (ap * 4 + i) * 336 + (aq * 4 + j) * 12 + h2;
      const int h = g / 784, n = g % 784;
      s += bf2f(q[(((size_t)b * H_ + h) * N_ + NMT_ + n) * HD_ + lane]);
    }
  agent[((size_t)b * H_ + h2) * 4096 + a * 64 + lane] = f2bf(s * 0.0625f);
}

// ------------------------------------------------------------------
// Flash attention — R16 measured-best version (vectorized Ps/Ss).
// ------------------------------------------------------------------
__global__ __launch_bounds__(256, 3) void flash_attn(
    const u16* __restrict__ Q, int q_bh_str, int q_base, int q_row_max, int q_valid,
    const u16* __restrict__ K, int k_bh_str, int k_row_max,
    const u16* __restrict__ Vt, int vt_bh_str, int vt_pitch, int vt_col_max,
    int n_keys, int nkt,
    u16* __restrict__ cch, int b0,
    u16* __restrict__ avT, int mode) {
  __shared__ u16 Qs[4096], Ks[4096], Vts[4096], Ps[4096];
  __shared__ float Ss[64][68];
  __shared__ float mS[64], lS[64], aS[64];

  const int tid = threadIdx.x, bh = blockIdx.x;
  const int q0 = q_base + blockIdx.y * 56;
  const int lane = tid & 63, w = tid >> 6;
  const int fr = lane & 15, ko = lane >> 4;

  const u16* Qb = Q + (size_t)bh * q_bh_str;
  const u16* Kb = K + (size_t)bh * k_bh_str;
  const u16* Vb = Vt + (size_t)bh * vt_bh_str;

#pragma unroll
  for (int i = 0; i < 2; ++i) {
    const int ch = tid + i * 256;
    const int row = ch >> 3, c8 = (ch & 7) << 3;
    const int qr = min(q0 + row, q_row_max);
    const short8 v = *(const short8*)&Qb[(size_t)qr * 64 + c8];
    *(short8*)&Qs[(row * 64 + c8) ^ ((row & 7) << 3)] = v;
  }
  if (tid < 64) { mS[tid] = NEGBIG_; lS[tid] = 0.f; aS[tid] = 0.f; }

  f32x4 oacc[4];
#pragma unroll
  for (int d = 0; d < 4; ++d) oacc[d] = (f32x4)0.f;

  for (int kt = 0; kt < nkt; ++kt) {
#pragma unroll
    for (int i = 0; i < 2; ++i) {
      const int ch = tid + i * 256;
      const int row = ch >> 3, c8 = (ch & 7) << 3;
      const int kr = min(kt * 64 + row, k_row_max);
      const short8 v = *(const short8*)&Kb[(size_t)kr * 64 + c8];
      *(short8*)&Ks[(row * 64 + c8) ^ ((row & 7) << 3)] = v;
    }
#pragma unroll
    for (int i = 0; i < 2; ++i) {
      const int ch = tid + i * 256;
      const int row = ch >> 3, c8 = (ch & 7) << 3;
      const int col8 = kt * 64 + c8;
      const u16* src = &Vb[(size_t)row * vt_pitch];
      short8 v;
      if (col8 + 8 <= vt_col_max) {
        v = *(const short8*)&src[col8];
      } else {
#pragma unroll
        for (int e = 0; e < 8; ++e) v[e] = (short)src[min(col8 + e, vt_col_max - 1)];
      }
      *(short8*)&Vts[(row * 64 + c8) ^ ((row & 7) << 3)] = v;
    }
    __syncthreads();

    short8 aq[2];
#pragma unroll
    for (int s = 0; s < 2; ++s)
      aq[s] = *(const short8*)&Qs[((w * 16 + fr) * 64 + s * 32 + ko * 8) ^ ((fr & 7) << 3)];
#pragma unroll
    for (int j = 0; j < 4; ++j) {
      f32x4 sa = (f32x4)0.f;
#pragma unroll
      for (int s = 0; s < 2; ++s) {
        const short8 bk = *(const short8*)&Ks[((j * 16 + fr) * 64 + s * 32 + ko * 8) ^ ((fr & 7) << 3)];
        sa = __builtin_amdgcn_mfma_f32_16x16x32_bf16(aq[s], bk, sa, 0, 0, 0);
      }
      const int colg = kt * 64 + j * 16 + fr;
      const bool maskc = (colg >= n_keys);
#pragma unroll
      for (int r = 0; r < 4; ++r) {
        const int srow = w * 16 + ko * 4 + r;
        Ss[srow][j * 16 + fr] = maskc ? NEGBIG_ : sa[r] * 0.125f;
      }
    }
    __syncthreads();

    {
      const int r = tid >> 2, jj = tid & 3;
      float sv[16];
      float mx = NEGBIG_;
#pragma unroll
      for (int cc = 0; cc < 4; ++cc) {
        const f32x4 v4 = *(const f32x4*)&Ss[r][jj * 16 + cc * 4];
#pragma unroll
        for (int e = 0; e < 4; ++e) {
          sv[cc * 4 + e] = v4[e];
          mx = fmaxf(mx, v4[e]);
        }
      }
      mx = fmaxf(mx, __shfl_xor(mx, 1));
      mx = fmaxf(mx, __shfl_xor(mx, 2));
      const float mold = mS[r];
      const float mnew = fmaxf(mold, mx);
      float sum = 0.f;
      const int pbase = r * 64 + jj * 16;
      const int px = (r & 7) << 3;
#pragma unroll
      for (int hh = 0; hh < 2; ++hh) {
        short8 ph;
#pragma unroll
        for (int c = 0; c < 8; ++c) {
          const bool mk = (kt * 64 + jj * 16 + hh * 8 + c) >= n_keys;
          const float p = mk ? 0.f : __expf(sv[hh * 8 + c] - mnew);
          sum += p;
          ph[c] = (short)f2bf(p);
        }
        *(short8*)&Ps[(pbase + hh * 8) ^ px] = ph;
      }
      sum += __shfl_xor(sum, 1);
      sum += __shfl_xor(sum, 2);
      if (jj == 0) {
        const float alpha = __expf(mold - mnew);
        aS[r] = alpha;
        lS[r] = lS[r] * alpha + sum;
        mS[r] = mnew;
      }
    }
    __syncthreads();

    float al[4];
#pragma unroll
    for (int r = 0; r < 4; ++r) al[r] = aS[w * 16 + ko * 4 + r];
    short8 ap[2];
#pragma unroll
    for (int s = 0; s < 2; ++s)
      ap[s] = *(const short8*)&Ps[((w * 16 + fr) * 64 + s * 32 + ko * 8) ^ ((fr & 7) << 3)];
#pragma unroll
    for (int dj = 0; dj < 4; ++dj) {
      f32x4 o = oacc[dj];
#pragma unroll
      for (int r = 0; r < 4; ++r) o[r] *= al[r];
#pragma unroll
      for (int s = 0; s < 2; ++s) {
        const short8 bv = *(const short8*)&Vts[((dj * 16 + fr) * 64 + s * 32 + ko * 8) ^ ((fr & 7) << 3)];
        o = __builtin_amdgcn_mfma_f32_16x16x32_bf16(ap[s], bv, o, 0, 0, 0);
      }
      oacc[dj] = o;
    }
    __syncthreads();
  }

  float linv[4];
#pragma unroll
  for (int r = 0; r < 4; ++r) linv[r] = 1.f / fmaxf(lS[w * 16 + ko * 4 + r], 1e-30f);

  if (mode == 0) {
    const int b = bh / H_, h = bh % H_;
#pragma unroll
    for (int dj = 0; dj < 4; ++dj)
#pragma unroll
      for (int r = 0; r < 4; ++r) {
        const int rowl = w * 16 + ko * 4 + r;
        if (rowl < q_valid) {
          const size_t m = (size_t)(b0 + b) * N_ + q0 + rowl;
          cch[m * 768 + h * 64 + dj * 16 + fr] = f2bf(oacc[dj][r] * linv[r]);
        }
      }
  } else {
#pragma unroll
    for (int dj = 0; dj < 4; ++dj)
#pragma unroll
      for (int r = 0; r < 4; ++r) {
        const int a = w * 16 + ko * 4 + r;
        avT[(size_t)bh * 4096 + (dj * 16 + fr) * 64 + a] = f2bf(oacc[dj][r] * linv[r]);
      }
  }
}

// ------------------------------------------------------------------
extern "C" void kernel_launch(void* const* d_in, const int* in_sizes, int n_in,
                              void* d_out, int out_size, void* d_ws,
                              size_t ws_size, hipStream_t stream) {
  const float* x = (const float*)d_in[0];
  const float* qkv_w = (const float*)d_in[1];
  const float* qkv_b = (const float*)d_in[2];
  const float* proj_w = (const float*)d_in[3];
  const float* proj_b = (const float*)d_in[4];
  float* out = (float*)d_out;
  u16* ws = (u16*)d_ws;

  const size_t XBF = 28901376ull;
  const size_t QW = 2304ull * 768;
  const size_t PW = 768ull * 768;
  const size_t QKV1 = (size_t)H_ * N_ * HD_;
  const size_t AG1 = (size_t)H_ * 64 * 64;

  size_t o = 0;
  u16* xbf = ws + o; o += XBF;
  u16* qwh = ws + o; o += QW;
  u16* pwh = ws + o; o += PW;
  u16* pwl = ws + o; o += PW;
  u16* cch = ws + o; o += XBF;
  const size_t fixed_sh = o;
  const size_t per_sh = 3 * QKV1 + 2 * AG1;

  int cb = 1;
  const int cands[6] = {32, 16, 8, 4, 2, 1};
  for (int i = 0; i < 6; ++i)
    if ((fixed_sh + (size_t)cands[i] * per_sh) * 2 <= ws_size) { cb = cands[i]; break; }

  u16* qb = ws + o; o += cb * QKV1;
  u16* kb = ws + o; o += cb * QKV1;
  u16* vb = ws + o; o += cb * QKV1;
  u16* agent = ws + o; o += cb * AG1;
  u16* avT = ws + o; o += cb * AG1;

  split_all<<<3584, 256, 0, stream>>>(x, xbf, (int)(XBF / 4),
                                      qkv_w, qwh, (int)(QW / 4),
                                      proj_w, pwh, pwl, (int)(PW / 4));

  const int nch = B_ / cb;
  for (int chn = 0; chn < nch; ++chn) {
    const int b0 = chn * cb;
    const int Mch = cb * N_;
    const int nrow = (Mch + 255) / 256;
    gemm_qkv<<<dim3(nrow * 18), 512, 0, stream>>>(
        xbf + (size_t)b0 * N_ * 768, qwh, qkv_b, qb, kb, vb, Mch);
    agent_pool<<<dim3(cb * 192), 256, 0, stream>>>(qb, agent);
    // agent attention: 49 agents vs all 1176 keys -> avT (d-major)
    flash_attn<<<dim3(cb * H_, 1), 256, 0, stream>>>(
        agent, 4096, 0, 48, AG_, kb, N_ * HD_, N_ - 1,
        vb, N_ * HD_, N_, N_, N_, 19, nullptr, b0, avT, 1);
    // MT attention: 392 x 392
    flash_attn<<<dim3(cb * H_, 7), 256, 0, stream>>>(
        qb, N_ * HD_, 0, N_ - 1, 56, kb, N_ * HD_, N_ - 1,
        vb, N_ * HD_, N_, N_, NMT_, 7, cch, b0, nullptr, 0);
    // q_s attention: 784 x 49 agents
    flash_attn<<<dim3(cb * H_, 14), 256, 0, stream>>>(
        qb, N_ * HD_, NMT_, N_ - 1, 56, agent, 4096, 63,
        avT, 4096, 64, 64, AG_, 1, cch, b0, nullptr, 0);
  }
  gemm_proj<<<dim3(147 * 6), 512, 0, stream>>>(cch, pwh, pwl, proj_b, out);
}

// Round 21
// 449.589 us; speedup vs baseline: 1.2172x; 1.0484x over previous
//
#include <hip/hip_runtime.h>

typedef __attribute__((ext_vector_type(8))) short short8;
typedef __attribute__((ext_vector_type(4))) short short4v;
typedef __attribute__((ext_vector_type(4))) float f32x4;
typedef unsigned short u16;

#define B_    32
#define N_    1176
#define C_    768
#define H_    12
#define HD_   64
#define NMT_  392
#define AG_   49
#define NEGBIG_ (-1.0e4f)

__device__ __forceinline__ u16 f2bf(float f) {
  unsigned u = __float_as_uint(f);
  unsigned r = (u + 0x7fffu + ((u >> 16) & 1u)) >> 16;
  return (u16)r;
}
__device__ __forceinline__ float bf2f(u16 s) {
  return __uint_as_float(((unsigned)s) << 16);
}

// Bijective XCD-chunk swizzle (m204).
__device__ __forceinline__ int xcd_swz(int g, int nwg) {
  const int q = nwg >> 3, r = nwg & 7;
  const int xcd = g & 7, off = g >> 3;
  return (xcd < r ? xcd * (q + 1) : r * (q + 1) + (xcd - r) * q) + off;
}

// ------------------------------------------------------------------
// Combined fp32->bf16 split for x (hi), qkv_w (hi), proj_w (hi+lo).
// ------------------------------------------------------------------
__global__ __launch_bounds__(256) void split_all(
    const float* __restrict__ x, u16* __restrict__ xbf, int n4x,
    const float* __restrict__ qw, u16* __restrict__ qwh, int n4q,
    const float* __restrict__ pw, u16* __restrict__ pwh,
    u16* __restrict__ pwl, int n4p) {
  const int bid = blockIdx.x;
  const float* in;
  u16 *hi, *lo = nullptr;
  int n4, i0, nblk;
  if (bid < 2048) {
    in = x; hi = xbf; n4 = n4x; i0 = bid; nblk = 2048;
  } else if (bid < 3072) {
    in = qw; hi = qwh; n4 = n4q; i0 = bid - 2048; nblk = 1024;
  } else {
    in = pw; hi = pwh; lo = pwl; n4 = n4p; i0 = bid - 3072; nblk = 512;
  }
  int i = i0 * 256 + threadIdx.x;
  const int stride = nblk * 256;
  const bool dolo = (lo != nullptr);
  for (; i < n4; i += stride) {
    const float4 v = ((const float4*)in)[i];
    const float f[4] = {v.x, v.y, v.z, v.w};
    short4v h, l;
#pragma unroll
    for (int e = 0; e < 4; ++e) {
      u16 hb = f2bf(f[e]);
      h[e] = (short)hb;
      l[e] = (short)f2bf(f[e] - bf2f(hb));
    }
    ((short4v*)hi)[i] = h;
    if (dolo) ((short4v*)lo)[i] = l;
  }
}

// ------------------------------------------------------------------
// QKV GEMM R19: 256x128 tile, 512 threads, BK=64 — unchanged.
// ------------------------------------------------------------------
__global__ __launch_bounds__(512, 4) void gemm_qkv(
    const u16* __restrict__ A, const u16* __restrict__ Bw,
    const float* __restrict__ bias, u16* __restrict__ qb, u16* __restrict__ kb,
    u16* __restrict__ vb, int Mch) {
  __shared__ u16 SH[24576];
  u16* As = SH;
  u16* Bs = SH + 16384;
  const int tid = threadIdx.x;
  const int swz = xcd_swz(blockIdx.x, gridDim.x);
  const int half = gridDim.x >> 1;
  const int cg = swz / half;
  const int rem = swz - cg * half;
  const int brow = rem / 9;
  const int bcol = cg * 9 + (rem - brow * 9);
  const int m0 = brow * 256, c0 = bcol * 128;
  const int lane = tid & 63, w = tid >> 6;
  const int wr = w >> 1, wc = w & 1;
  const int fr = lane & 15, ko = lane >> 4;
  const int lsw = (lane * 8) ^ (ko << 4);

  f32x4 acc[4][4];
#pragma unroll
  for (int m = 0; m < 4; ++m)
#pragma unroll
    for (int n = 0; n < 4; ++n) acc[m][n] = (f32x4)0.f;

  short8 ra[4], rb[2];
  auto LOADG = [&](int kt) {
#pragma unroll
    for (int i = 0; i < 4; ++i) {
      const int ch = tid + i * 512;
      const int row = ch >> 3, slotk = ch & 7;
      const int ar = min(m0 + row, Mch - 1);
      ra[i] = *(const short8*)&A[(size_t)ar * 768 + kt * 64 + slotk * 8];
    }
#pragma unroll
    for (int i = 0; i < 2; ++i) {
      const int ch = tid + i * 512;
      const int row = ch >> 3, slotk = ch & 7;
      rb[i] = *(const short8*)&Bw[(size_t)(c0 + row) * 768 + kt * 64 + slotk * 8];
    }
  };
  auto WRITE = [&]() {
#pragma unroll
    for (int i = 0; i < 4; ++i) {
      const int ch = tid + i * 512;
      const int row = ch >> 3, slotk = ch & 7;
      const int s = slotk >> 2, sl = slotk & 3;
      const int off = (row >> 4) * 1024 + s * 512 +
                      ((sl * 128 + (row & 15) * 8) ^ (sl << 4));
      *(short8*)&As[off] = ra[i];
    }
#pragma unroll
    for (int i = 0; i < 2; ++i) {
      const int ch = tid + i * 512;
      const int row = ch >> 3, slotk = ch & 7;
      const int s = slotk >> 2, sl = slotk & 3;
      const int off = (row >> 4) * 1024 + s * 512 +
                      ((sl * 128 + (row & 15) * 8) ^ (sl << 4));
      *(short8*)&Bs[off] = rb[i];
    }
  };

  LOADG(0);
  for (int kt = 0; kt < 12; ++kt) {
    __syncthreads();
    WRITE();
    if (kt < 11) LOADG(kt + 1);
    __syncthreads();
#pragma unroll
    for (int s = 0; s < 2; ++s) {
      short8 af[4], bfr[4];
#pragma unroll
      for (int m = 0; m < 4; ++m)
        af[m] = *(const short8*)&As[((wr * 4 + m) * 2 + s) * 512 + lsw];
#pragma unroll
      for (int n = 0; n < 4; ++n)
        bfr[n] = *(const short8*)&Bs[((wc * 4 + n) * 2 + s) * 512 + lsw];
#pragma unroll
      for (int m = 0; m < 4; ++m)
#pragma unroll
        for (int n = 0; n < 4; ++n)
          acc[m][n] = __builtin_amdgcn_mfma_f32_16x16x32_bf16(af[m], bfr[n], acc[m][n], 0, 0, 0);
    }
  }

  const int t = c0 / 768;
  const int hbase = (c0 % 768) >> 6;
#pragma unroll
  for (int p2 = 0; p2 < 2; ++p2) {
    __syncthreads();
    if ((wr >> 1) == p2) {
      const int lbase = (wr & 1) * 64;
      if (t < 2) {
#pragma unroll
        for (int n = 0; n < 4; ++n) {
          const int col = wc * 64 + n * 16 + fr;
          const float bv = bias[c0 + col];
#pragma unroll
          for (int m = 0; m < 4; ++m)
#pragma unroll
            for (int r = 0; r < 4; ++r) {
              const int lrow = lbase + m * 16 + ko * 4 + r;
              SH[lrow * 136 + col] = f2bf(acc[m][n][r] + bv);
            }
        }
      } else {
#pragma unroll
        for (int n = 0; n < 4; ++n) {
          const int col = wc * 64 + n * 16 + fr;
          const float bv = bias[c0 + col];
#pragma unroll
          for (int m = 0; m < 4; ++m)
#pragma unroll
            for (int r = 0; r < 4; ++r) {
              const int lrow = lbase + m * 16 + ko * 4 + r;
              SH[col * 136 + lrow] = f2bf(acc[m][n][r] + bv);
            }
        }
      }
    }
    __syncthreads();
    if (t < 2) {
      u16* dst = (t == 0) ? qb : kb;
#pragma unroll
      for (int it = 0; it < 4; ++it) {
        const int idx = tid + it * 512;
        const int rt = idx >> 4, half2 = (idx >> 3) & 1, p = idx & 7;
        const int mg = m0 + p2 * 128 + rt;
        if (mg < Mch) {
          const int bl = mg / N_, nt = mg - bl * N_;
          const short8 vv = *(const short8*)&SH[rt * 136 + half2 * 64 + p * 8];
          *(short8*)&dst[(((size_t)bl * H_ + hbase + half2) * N_ + nt) * 64 + p * 8] = vv;
        }
      }
    } else {
#pragma unroll
      for (int it = 0; it < 4; ++it) {
        const int idx = tid + it * 512;
        const int ct = idx >> 4, tc = idx & 15;
        const int mg0 = m0 + p2 * 128 + tc * 8;
        if (mg0 < Mch) {
          const int bl = mg0 / N_, nt = mg0 - bl * N_;
          const int d = ct & 63, hh = hbase + (ct >> 6);
          const short8 vv = *(const short8*)&SH[ct * 136 + tc * 8];
          *(short8*)&vb[(((size_t)bl * H_ + hh) * 64 + d) * N_ + nt] = vv;
        }
      }
    }
  }
}

// ------------------------------------------------------------------
// Proj GEMM R19b: 256x128 tile, 512 threads, 2-term — unchanged.
// ------------------------------------------------------------------
__global__ __launch_bounds__(512, 2) void gemm_proj(
    const u16* __restrict__ Ahg, const u16* __restrict__ Bhg,
    const u16* __restrict__ Blg, const float* __restrict__ bias,
    float* __restrict__ out) {
  __shared__ u16 Ah[16384], Bh[8192], Bl[8192];
  const int tid = threadIdx.x;
  const int swz = xcd_swz(blockIdx.x, gridDim.x);
  const int brow = swz / 6, bcol = swz - brow * 6;
  const int m0 = brow * 256, c0 = bcol * 128;
  const int lane = tid & 63, w = tid >> 6;
  const int wr = w >> 1, wc = w & 1;
  const int fr = lane & 15, ko = lane >> 4;
  const int lsw = (lane * 8) ^ (ko << 4);

  f32x4 acc[4][4];
#pragma unroll
  for (int m = 0; m < 4; ++m)
#pragma unroll
    for (int n = 0; n < 4; ++n) acc[m][n] = (f32x4)0.f;

  short8 ra[4], rbh[2], rbl[2];
  auto LOADG = [&](int kt) {
#pragma unroll
    for (int i = 0; i < 4; ++i) {
      const int ch = tid + i * 512;
      const int row = ch >> 3, slotk = ch & 7;
      ra[i] = *(const short8*)&Ahg[(size_t)(m0 + row) * 768 + kt * 64 + slotk * 8];
    }
#pragma unroll
    for (int i = 0; i < 2; ++i) {
      const int ch = tid + i * 512;
      const int row = ch >> 3, slotk = ch & 7;
      const size_t boff = (size_t)(c0 + row) * 768 + kt * 64 + slotk * 8;
      rbh[i] = *(const short8*)&Bhg[boff];
      rbl[i] = *(const short8*)&Blg[boff];
    }
  };
  auto WRITE = [&]() {
#pragma unroll
    for (int i = 0; i < 4; ++i) {
      const int ch = tid + i * 512;
      const int row = ch >> 3, slotk = ch & 7;
      const int s = slotk >> 2, sl = slotk & 3;
      const int off = (row >> 4) * 1024 + s * 512 +
                      ((sl * 128 + (row & 15) * 8) ^ (sl << 4));
      *(short8*)&Ah[off] = ra[i];
    }
#pragma unroll
    for (int i = 0; i < 2; ++i) {
      const int ch = tid + i * 512;
      const int row = ch >> 3, slotk = ch & 7;
      const int s = slotk >> 2, sl = slotk & 3;
      const int off = (row >> 4) * 1024 + s * 512 +
                      ((sl * 128 + (row & 15) * 8) ^ (sl << 4));
      *(short8*)&Bh[off] = rbh[i];
      *(short8*)&Bl[off] = rbl[i];
    }
  };

  LOADG(0);
  for (int kt = 0; kt < 12; ++kt) {
    __syncthreads();
    WRITE();
    if (kt < 11) LOADG(kt + 1);
    __syncthreads();
#pragma unroll
    for (int s = 0; s < 2; ++s) {
      short8 af[4], bh[4], bl[4];
#pragma unroll
      for (int m = 0; m < 4; ++m)
        af[m] = *(const short8*)&Ah[((wr * 4 + m) * 2 + s) * 512 + lsw];
#pragma unroll
      for (int n = 0; n < 4; ++n) {
        const int off = ((wc * 4 + n) * 2 + s) * 512 + lsw;
        bh[n] = *(const short8*)&Bh[off];
        bl[n] = *(const short8*)&Bl[off];
      }
#pragma unroll
      for (int m = 0; m < 4; ++m)
#pragma unroll
        for (int n = 0; n < 4; ++n) {
          acc[m][n] = __builtin_amdgcn_mfma_f32_16x16x32_bf16(af[m], bh[n], acc[m][n], 0, 0, 0);
          acc[m][n] = __builtin_amdgcn_mfma_f32_16x16x32_bf16(af[m], bl[n], acc[m][n], 0, 0, 0);
        }
    }
  }
#pragma unroll
  for (int n = 0; n < 4; ++n) {
    const int col = c0 + wc * 64 + n * 16 + fr;
    const float bv = bias[col];
#pragma unroll
    for (int m = 0; m < 4; ++m) {
      const int mg = m0 + wr * 64 + m * 16 + ko * 4;
#pragma unroll
      for (int r = 0; r < 4; ++r) out[(size_t)(mg + r) * 768 + col] = acc[m][n][r] + bv;
    }
  }
}

// ------------------------------------------------------------------
// Agent pooling (scrambled reshape); rows 49..63 zeroed.
// ------------------------------------------------------------------
__global__ __launch_bounds__(256) void agent_pool(const u16* __restrict__ q,
                                                  u16* __restrict__ agent) {
  const int wid = threadIdx.x >> 6;
  const int lane = threadIdx.x & 63;
  const int row = blockIdx.x * 4 + wid;
  const int rem = row % (H_ * 64);
  const int b = row / (H_ * 64);
  const int h2 = rem / 64;
  const int a = rem % 64;
  if (a >= AG_) {
    agent[((size_t)b * H_ + h2) * 4096 + a * 64 + lane] = 0;
    return;
  }
  const int ap = a / 7, aq = a % 7;
  float s = 0.f;
#pragma unroll
  for (int i = 0; i < 4; ++i)
#pragma unroll
    for (int j = 0; j < 4; ++j) {
      const int g = (ap * 4 + i) * 336 + (aq * 4 + j) * 12 + h2;
      const int h = g / 784, n = g % 784;
      s += bf2f(q[(((size_t)b * H_ + h) * N_ + NMT_ + n) * HD_ + lane]);
    }
  agent[((size_t)b * H_ + h2) * 4096 + a * 64 + lane] = f2bf(s * 0.0625f);
}

// ------------------------------------------------------------------
// Flash attention — R16 body, generic (used for agent attention).
// ------------------------------------------------------------------
__global__ __launch_bounds__(256, 3) void flash_attn(
    const u16* __restrict__ Q, int q_bh_str, int q_base, int q_row_max, int q_valid,
    const u16* __restrict__ K, int k_bh_str, int k_row_max,
    const u16* __restrict__ Vt, int vt_bh_str, int vt_pitch, int vt_col_max,
    int n_keys, int nkt,
    u16* __restrict__ cch, int b0,
    u16* __restrict__ avT, int mode) {
  __shared__ u16 Qs[4096], Ks[4096], Vts[4096], Ps[4096];
  __shared__ float Ss[64][68];
  __shared__ float mS[64], lS[64], aS[64];

  const int tid = threadIdx.x, bh = blockIdx.x;
  const int q0 = q_base + blockIdx.y * 56;
  const int lane = tid & 63, w = tid >> 6;
  const int fr = lane & 15, ko = lane >> 4;

  const u16* Qb = Q + (size_t)bh * q_bh_str;
  const u16* Kb = K + (size_t)bh * k_bh_str;
  const u16* Vb = Vt + (size_t)bh * vt_bh_str;

#pragma unroll
  for (int i = 0; i < 2; ++i) {
    const int ch = tid + i * 256;
    const int row = ch >> 3, c8 = (ch & 7) << 3;
    const int qr = min(q0 + row, q_row_max);
    const short8 v = *(const short8*)&Qb[(size_t)qr * 64 + c8];
    *(short8*)&Qs[(row * 64 + c8) ^ ((row & 7) << 3)] = v;
  }
  if (tid < 64) { mS[tid] = NEGBIG_; lS[tid] = 0.f; aS[tid] = 0.f; }

  f32x4 oacc[4];
#pragma unroll
  for (int d = 0; d < 4; ++d) oacc[d] = (f32x4)0.f;

  for (int kt = 0; kt < nkt; ++kt) {
#pragma unroll
    for (int i = 0; i < 2; ++i) {
      const int ch = tid + i * 256;
      const int row = ch >> 3, c8 = (ch & 7) << 3;
      const int kr = min(kt * 64 + row, k_row_max);
      const short8 v = *(const short8*)&Kb[(size_t)kr * 64 + c8];
      *(short8*)&Ks[(row * 64 + c8) ^ ((row & 7) << 3)] = v;
    }
#pragma unroll
    for (int i = 0; i < 2; ++i) {
      const int ch = tid + i * 256;
      const int row = ch >> 3, c8 = (ch & 7) << 3;
      const int col8 = kt * 64 + c8;
      const u16* src = &Vb[(size_t)row * vt_pitch];
      short8 v;
      if (col8 + 8 <= vt_col_max) {
        v = *(const short8*)&src[col8];
      } else {
#pragma unroll
        for (int e = 0; e < 8; ++e) v[e] = (short)src[min(col8 + e, vt_col_max - 1)];
      }
      *(short8*)&Vts[(row * 64 + c8) ^ ((row & 7) << 3)] = v;
    }
    __syncthreads();

    short8 aq[2];
#pragma unroll
    for (int s = 0; s < 2; ++s)
      aq[s] = *(const short8*)&Qs[((w * 16 + fr) * 64 + s * 32 + ko * 8) ^ ((fr & 7) << 3)];
#pragma unroll
    for (int j = 0; j < 4; ++j) {
      f32x4 sa = (f32x4)0.f;
#pragma unroll
      for (int s = 0; s < 2; ++s) {
        const short8 bk = *(const short8*)&Ks[((j * 16 + fr) * 64 + s * 32 + ko * 8) ^ ((fr & 7) << 3)];
        sa = __builtin_amdgcn_mfma_f32_16x16x32_bf16(aq[s], bk, sa, 0, 0, 0);
      }
      const int colg = kt * 64 + j * 16 + fr;
      const bool maskc = (colg >= n_keys);
#pragma unroll
      for (int r = 0; r < 4; ++r) {
        const int srow = w * 16 + ko * 4 + r;
        Ss[srow][j * 16 + fr] = maskc ? NEGBIG_ : sa[r] * 0.125f;
      }
    }
    __syncthreads();

    {
      const int r = tid >> 2, jj = tid & 3;
      float sv[16];
      float mx = NEGBIG_;
#pragma unroll
      for (int cc = 0; cc < 4; ++cc) {
        const f32x4 v4 = *(const f32x4*)&Ss[r][jj * 16 + cc * 4];
#pragma unroll
        for (int e = 0; e < 4; ++e) {
          sv[cc * 4 + e] = v4[e];
          mx = fmaxf(mx, v4[e]);
        }
      }
      mx = fmaxf(mx, __shfl_xor(mx, 1));
      mx = fmaxf(mx, __shfl_xor(mx, 2));
      const float mold = mS[r];
      const float mnew = fmaxf(mold, mx);
      float sum = 0.f;
      const int pbase = r * 64 + jj * 16;
      const int px = (r & 7) << 3;
#pragma unroll
      for (int hh = 0; hh < 2; ++hh) {
        short8 ph;
#pragma unroll
        for (int c = 0; c < 8; ++c) {
          const bool mk = (kt * 64 + jj * 16 + hh * 8 + c) >= n_keys;
          const float p = mk ? 0.f : __expf(sv[hh * 8 + c] - mnew);
          sum += p;
          ph[c] = (short)f2bf(p);
        }
        *(short8*)&Ps[(pbase + hh * 8) ^ px] = ph;
      }
      sum += __shfl_xor(sum, 1);
      sum += __shfl_xor(sum, 2);
      if (jj == 0) {
        const float alpha = __expf(mold - mnew);
        aS[r] = alpha;
        lS[r] = lS[r] * alpha + sum;
        mS[r] = mnew;
      }
    }
    __syncthreads();

    float al[4];
#pragma unroll
    for (int r = 0; r < 4; ++r) al[r] = aS[w * 16 + ko * 4 + r];
    short8 ap[2];
#pragma unroll
    for (int s = 0; s < 2; ++s)
      ap[s] = *(const short8*)&Ps[((w * 16 + fr) * 64 + s * 32 + ko * 8) ^ ((fr & 7) << 3)];
#pragma unroll
    for (int dj = 0; dj < 4; ++dj) {
      f32x4 o = oacc[dj];
#pragma unroll
      for (int r = 0; r < 4; ++r) o[r] *= al[r];
#pragma unroll
      for (int s = 0; s < 2; ++s) {
        const short8 bv = *(const short8*)&Vts[((dj * 16 + fr) * 64 + s * 32 + ko * 8) ^ ((fr & 7) << 3)];
        o = __builtin_amdgcn_mfma_f32_16x16x32_bf16(ap[s], bv, o, 0, 0, 0);
      }
      oacc[dj] = o;
    }
    __syncthreads();
  }

  float linv[4];
#pragma unroll
  for (int r = 0; r < 4; ++r) linv[r] = 1.f / fmaxf(lS[w * 16 + ko * 4 + r], 1e-30f);

  if (mode == 0) {
    const int b = bh / H_, h = bh % H_;
#pragma unroll
    for (int dj = 0; dj < 4; ++dj)
#pragma unroll
      for (int r = 0; r < 4; ++r) {
        const int rowl = w * 16 + ko * 4 + r;
        if (rowl < q_valid) {
          const size_t m = (size_t)(b0 + b) * N_ + q0 + rowl;
          cch[m * 768 + h * 64 + dj * 16 + fr] = f2bf(oacc[dj][r] * linv[r]);
        }
      }
  } else {
#pragma unroll
    for (int dj = 0; dj < 4; ++dj)
#pragma unroll
      for (int r = 0; r < 4; ++r) {
        const int a = w * 16 + ko * 4 + r;
        avT[(size_t)bh * 4096 + (dj * 16 + fr) * 64 + a] = f2bf(oacc[dj][r] * linv[r]);
      }
  }
}

// ------------------------------------------------------------------
// Fused MT + qs attention (R20b). y<7 -> MT q-tile y (392 keys, 7 kt,
// K=kb, V=vb); y>=7 -> qs q-tile y-7 (49 agent keys, 1 kt, K=agent,
// V=avT). Block-uniform select; V loads provably in-range for both.
// ------------------------------------------------------------------
__global__ __launch_bounds__(256, 3) void flash_mtqs(
    const u16* __restrict__ qb, const u16* __restrict__ kb,
    const u16* __restrict__ vb, const u16* __restrict__ agent,
    const u16* __restrict__ avT, u16* __restrict__ cch, int b0) {
  __shared__ u16 Qs[4096], Ks[4096], Vts[4096], Ps[4096];
  __shared__ float Ss[64][68];
  __shared__ float mS[64], lS[64], aS[64];

  const int tid = threadIdx.x, bh = blockIdx.x;
  const bool isqs = (blockIdx.y >= 7);
  const int qt = isqs ? (blockIdx.y - 7) : blockIdx.y;
  const int q0 = (isqs ? NMT_ : 0) + qt * 56;
  const int nkt = isqs ? 1 : 7;
  const int n_keys = isqs ? AG_ : NMT_;
  const int vt_pitch = isqs ? 64 : N_;
  const int k_row_max = isqs ? 63 : (N_ - 1);

  const int lane = tid & 63, w = tid >> 6;
  const int fr = lane & 15, ko = lane >> 4;

  const u16* Qb = qb + (size_t)bh * (N_ * HD_);
  const u16* Kb = (isqs ? agent : kb) + (size_t)bh * (isqs ? 4096 : N_ * HD_);
  const u16* Vb = (isqs ? avT : vb) + (size_t)bh * (isqs ? 4096 : N_ * HD_);

#pragma unroll
  for (int i = 0; i < 2; ++i) {
    const int ch = tid + i * 256;
    const int row = ch >> 3, c8 = (ch & 7) << 3;
    const int qr = min(q0 + row, N_ - 1);
    const short8 v = *(const short8*)&Qb[(size_t)qr * 64 + c8];
    *(short8*)&Qs[(row * 64 + c8) ^ ((row & 7) << 3)] = v;
  }
  if (tid < 64) { mS[tid] = NEGBIG_; lS[tid] = 0.f; aS[tid] = 0.f; }

  f32x4 oacc[4];
#pragma unroll
  for (int d = 0; d < 4; ++d) oacc[d] = (f32x4)0.f;

  for (int kt = 0; kt < nkt; ++kt) {
#pragma unroll
    for (int i = 0; i < 2; ++i) {
      const int ch = tid + i * 256;
      const int row = ch >> 3, c8 = (ch & 7) << 3;
      const int kr = min(kt * 64 + row, k_row_max);
      const short8 v = *(const short8*)&Kb[(size_t)kr * 64 + c8];
      *(short8*)&Ks[(row * 64 + c8) ^ ((row & 7) << 3)] = v;
    }
    // V loads always in-range: mt max col 447 < 1176; qs max col 63 < 64.
#pragma unroll
    for (int i = 0; i < 2; ++i) {
      const int ch = tid + i * 256;
      const int row = ch >> 3, c8 = (ch & 7) << 3;
      const short8 v = *(const short8*)&Vb[(size_t)row * vt_pitch + kt * 64 + c8];
      *(short8*)&Vts[(row * 64 + c8) ^ ((row & 7) << 3)] = v;
    }
    __syncthreads();

    short8 aq[2];
#pragma unroll
    for (int s = 0; s < 2; ++s)
      aq[s] = *(const short8*)&Qs[((w * 16 + fr) * 64 + s * 32 + ko * 8) ^ ((fr & 7) << 3)];
#pragma unroll
    for (int j = 0; j < 4; ++j) {
      f32x4 sa = (f32x4)0.f;
#pragma unroll
      for (int s = 0; s < 2; ++s) {
        const short8 bk = *(const short8*)&Ks[((j * 16 + fr) * 64 + s * 32 + ko * 8) ^ ((fr & 7) << 3)];
        sa = __builtin_amdgcn_mfma_f32_16x16x32_bf16(aq[s], bk, sa, 0, 0, 0);
      }
      const int colg = kt * 64 + j * 16 + fr;
      const bool maskc = (colg >= n_keys);
#pragma unroll
      for (int r = 0; r < 4; ++r) {
        const int srow = w * 16 + ko * 4 + r;
        Ss[srow][j * 16 + fr] = maskc ? NEGBIG_ : sa[r] * 0.125f;
      }
    }
    __syncthreads();

    {
      const int r = tid >> 2, jj = tid & 3;
      float sv[16];
      float mx = NEGBIG_;
#pragma unroll
      for (int cc = 0; cc < 4; ++cc) {
        const f32x4 v4 = *(const f32x4*)&Ss[r][jj * 16 + cc * 4];
#pragma unroll
        for (int e = 0; e < 4; ++e) {
          sv[cc * 4 + e] = v4[e];
          mx = fmaxf(mx, v4[e]);
        }
      }
      mx = fmaxf(mx, __shfl_xor(mx, 1));
      mx = fmaxf(mx, __shfl_xor(mx, 2));
      const float mold = mS[r];
      const float mnew = fmaxf(mold, mx);
      float sum = 0.f;
      const int pbase = r * 64 + jj * 16;
      const int px = (r & 7) << 3;
#pragma unroll
      for (int hh = 0; hh < 2; ++hh) {
        short8 ph;
#pragma unroll
        for (int c = 0; c < 8; ++c) {
          const bool mk = (kt * 64 + jj * 16 + hh * 8 + c) >= n_keys;
          const float p = mk ? 0.f : __expf(sv[hh * 8 + c] - mnew);
          sum += p;
          ph[c] = (short)f2bf(p);
        }
        *(short8*)&Ps[(pbase + hh * 8) ^ px] = ph;
      }
      sum += __shfl_xor(sum, 1);
      sum += __shfl_xor(sum, 2);
      if (jj == 0) {
        const float alpha = __expf(mold - mnew);
        aS[r] = alpha;
        lS[r] = lS[r] * alpha + sum;
        mS[r] = mnew;
      }
    }
    __syncthreads();

    float al[4];
#pragma unroll
    for (int r = 0; r < 4; ++r) al[r] = aS[w * 16 + ko * 4 + r];
    short8 ap[2];
#pragma unroll
    for (int s = 0; s < 2; ++s)
      ap[s] = *(const short8*)&Ps[((w * 16 + fr) * 64 + s * 32 + ko * 8) ^ ((fr & 7) << 3)];
#pragma unroll
    for (int dj = 0; dj < 4; ++dj) {
      f32x4 o = oacc[dj];
#pragma unroll
      for (int r = 0; r < 4; ++r) o[r] *= al[r];
#pragma unroll
      for (int s = 0; s < 2; ++s) {
        const short8 bv = *(const short8*)&Vts[((dj * 16 + fr) * 64 + s * 32 + ko * 8) ^ ((fr & 7) << 3)];
        o = __builtin_amdgcn_mfma_f32_16x16x32_bf16(ap[s], bv, o, 0, 0, 0);
      }
      oacc[dj] = o;
    }
    __syncthreads();
  }

  float linv[4];
#pragma unroll
  for (int r = 0; r < 4; ++r) linv[r] = 1.f / fmaxf(lS[w * 16 + ko * 4 + r], 1e-30f);

  const int b = bh / H_, h = bh % H_;
#pragma unroll
  for (int dj = 0; dj < 4; ++dj)
#pragma unroll
    for (int r = 0; r < 4; ++r) {
      const int rowl = w * 16 + ko * 4 + r;
      if (rowl < 56) {
        const size_t m = (size_t)(b0 + b) * N_ + q0 + rowl;
        cch[m * 768 + h * 64 + dj * 16 + fr] = f2bf(oacc[dj][r] * linv[r]);
      }
    }
}

// ------------------------------------------------------------------
extern "C" void kernel_launch(void* const* d_in, const int* in_sizes, int n_in,
                              void* d_out, int out_size, void* d_ws,
                              size_t ws_size, hipStream_t stream) {
  const float* x = (const float*)d_in[0];
  const float* qkv_w = (const float*)d_in[1];
  const float* qkv_b = (const float*)d_in[2];
  const float* proj_w = (const float*)d_in[3];
  const float* proj_b = (const float*)d_in[4];
  float* out = (float*)d_out;
  u16* ws = (u16*)d_ws;

  const size_t XBF = 28901376ull;
  const size_t QW = 2304ull * 768;
  const size_t PW = 768ull * 768;
  const size_t QKV1 = (size_t)H_ * N_ * HD_;
  const size_t AG1 = (size_t)H_ * 64 * 64;

  size_t o = 0;
  u16* xbf = ws + o; o += XBF;
  u16* qwh = ws + o; o += QW;
  u16* pwh = ws + o; o += PW;
  u16* pwl = ws + o; o += PW;
  u16* cch = ws + o; o += XBF;
  const size_t fixed_sh = o;
  const size_t per_sh = 3 * QKV1 + 2 * AG1;

  int cb = 1;
  const int cands[6] = {32, 16, 8, 4, 2, 1};
  for (int i = 0; i < 6; ++i)
    if ((fixed_sh + (size_t)cands[i] * per_sh) * 2 <= ws_size) { cb = cands[i]; break; }

  u16* qb = ws + o; o += cb * QKV1;
  u16* kb = ws + o; o += cb * QKV1;
  u16* vb = ws + o; o += cb * QKV1;
  u16* agent = ws + o; o += cb * AG1;
  u16* avT = ws + o; o += cb * AG1;

  split_all<<<3584, 256, 0, stream>>>(x, xbf, (int)(XBF / 4),
                                      qkv_w, qwh, (int)(QW / 4),
                                      proj_w, pwh, pwl, (int)(PW / 4));

  const int nch = B_ / cb;
  for (int chn = 0; chn < nch; ++chn) {
    const int b0 = chn * cb;
    const int Mch = cb * N_;
    const int nrow = (Mch + 255) / 256;
    gemm_qkv<<<dim3(nrow * 18), 512, 0, stream>>>(
        xbf + (size_t)b0 * N_ * 768, qwh, qkv_b, qb, kb, vb, Mch);
    agent_pool<<<dim3(cb * 192), 256, 0, stream>>>(qb, agent);
    // agent attention: 49 agents vs all 1176 keys -> avT (d-major)
    flash_attn<<<dim3(cb * H_, 1), 256, 0, stream>>>(
        agent, 4096, 0, 48, AG_, kb, N_ * HD_, N_ - 1,
        vb, N_ * HD_, N_, N_, N_, 19, nullptr, b0, avT, 1);
    // fused MT (y<7) + qs (y>=7) attention
    flash_mtqs<<<dim3(cb * H_, 21), 256, 0, stream>>>(
        qb, kb, vb, agent, avT, cch, b0);
  }
  gemm_proj<<<dim3(147 * 6), 512, 0, stream>>>(cch, pwh, pwl, proj_b, out);
}